// Round 1
// baseline (1033.428 us; speedup 1.0000x reference)
//
#include <hip/hip_runtime.h>
#include <math.h>

constexpr int NSEQ = 192;
constexpr int DIM  = 128;
constexpr int NH   = 4;
constexpr int DHEAD = 32;
constexpr int MROWS = NSEQ * NSEQ; // 36864

// ---------------- LayerNorm (+ optional bias-projection, + optional transpose) ----------
// One wave per row of 128. Computes xn = (x-mu)*rsqrt(var+eps)*g+b, written to xa
// (transposed row index if trans). If wb != null also computes
// bias[h, i, j] = sum_d x[i,j,d]*wb[d,h]  (always untransposed indices).
__global__ __launch_bounds__(256)
void ln_bias_kernel(const float* __restrict__ x, const float* __restrict__ g,
                    const float* __restrict__ b, const float* __restrict__ wb,
                    float* __restrict__ xa, float* __restrict__ bias, int trans)
{
    int wid  = threadIdx.x >> 6;
    int lane = threadIdx.x & 63;
    int row  = blockIdx.x * 4 + wid;
    const float* xr = x + (size_t)row * DIM;
    float x0 = xr[lane], x1 = xr[lane + 64];
    float s = x0 + x1, sq = x0 * x0 + x1 * x1;
    #pragma unroll
    for (int off = 32; off > 0; off >>= 1) {
        s  += __shfl_down(s, off);
        sq += __shfl_down(sq, off);
    }
    s = __shfl(s, 0); sq = __shfl(sq, 0);
    float mu  = s * (1.0f / 128.0f);
    float var = sq * (1.0f / 128.0f) - mu * mu;
    float rs  = rsqrtf(var + 1e-5f);
    float y0 = (x0 - mu) * rs * g[lane]      + b[lane];
    float y1 = (x1 - mu) * rs * g[lane + 64] + b[lane + 64];
    int orow = row;
    if (trans) { int i = row / NSEQ, j = row % NSEQ; orow = j * NSEQ + i; }
    float* yr = xa + (size_t)orow * DIM;
    yr[lane] = y0; yr[lane + 64] = y1;
    if (wb) {
        #pragma unroll
        for (int h = 0; h < NH; ++h) {
            float bh = x0 * wb[lane * NH + h] + x1 * wb[(lane + 64) * NH + h];
            #pragma unroll
            for (int off = 32; off > 0; off >>= 1) bh += __shfl_down(bh, off);
            if (lane == 0) bias[(size_t)h * MROWS + row] = bh;
        }
    }
}

// ---------------- Generic fp32 GEMM: C[M,NC] = A[M,K] @ B[K, ldb](cols bcol..) ----------
enum { EPI_SCALE = 0, EPI_NONE = 1, EPI_SIG = 2, EPI_RES = 3, EPI_RES_T = 4 };

template<int EPI>
__global__ __launch_bounds__(256)
void gemm_kernel(const float* __restrict__ A, const float* __restrict__ B,
                 int ldb, int bcol,
                 const float* __restrict__ bias, const float* __restrict__ resid,
                 float* __restrict__ C, int NC, int K, float scale)
{
    __shared__ float As[64][65];
    __shared__ float Bs[64][65];
    int tid = threadIdx.x;
    int tx = tid & 15, ty = tid >> 4;
    int m0 = blockIdx.x * 64, n0 = blockIdx.y * 64;
    float acc[4][4] = {};
    for (int k0 = 0; k0 < K; k0 += 64) {
        #pragma unroll
        for (int i = 0; i < 16; ++i) {
            int idx = tid + i * 256;
            int r = idx >> 6, c = idx & 63;
            As[r][c] = A[(size_t)(m0 + r) * K + k0 + c];
            Bs[r][c] = B[(size_t)(k0 + r) * ldb + bcol + n0 + c];
        }
        __syncthreads();
        #pragma unroll
        for (int kk = 0; kk < 64; ++kk) {
            float a[4], bb[4];
            #pragma unroll
            for (int i = 0; i < 4; ++i) a[i] = As[ty * 4 + i][kk];
            #pragma unroll
            for (int j = 0; j < 4; ++j) bb[j] = Bs[kk][tx * 4 + j];
            #pragma unroll
            for (int i = 0; i < 4; ++i)
                #pragma unroll
                for (int j = 0; j < 4; ++j)
                    acc[i][j] = fmaf(a[i], bb[j], acc[i][j]);
        }
        __syncthreads();
    }
    #pragma unroll
    for (int i = 0; i < 4; ++i) {
        int m = m0 + ty * 4 + i;
        #pragma unroll
        for (int j = 0; j < 4; ++j) {
            int n = n0 + tx * 4 + j;
            float v = acc[i][j];
            if (EPI == EPI_SCALE) {
                C[(size_t)m * NC + n] = v * scale;
            } else if (EPI == EPI_NONE) {
                C[(size_t)m * NC + n] = v;
            } else if (EPI == EPI_SIG) {
                C[(size_t)m * NC + n] = 1.0f / (1.0f + __expf(-(v + bias[n])));
            } else {
                int row = m;
                if (EPI == EPI_RES_T) row = (m % NSEQ) * NSEQ + (m / NSEQ);
                C[(size_t)row * NC + n] = v + bias[n] + resid[(size_t)row * NC + n];
            }
        }
    }
}

// ---------------- GEGLU GEMM: C[M,512] = (A@w1[:, :512]+b1a) * gelu(A@w1[:,512:]+b1g) ---
__global__ __launch_bounds__(256)
void gemm_geglu_kernel(const float* __restrict__ A, const float* __restrict__ B,
                       const float* __restrict__ b1, float* __restrict__ C)
{
    __shared__ float As [64][65];
    __shared__ float Bs [64][65];
    __shared__ float Bs2[64][65];
    int tid = threadIdx.x;
    int tx = tid & 15, ty = tid >> 4;
    int m0 = blockIdx.x * 64, n0 = blockIdx.y * 64;
    float acc[4][4] = {}, acc2[4][4] = {};
    for (int k0 = 0; k0 < 128; k0 += 64) {
        #pragma unroll
        for (int i = 0; i < 16; ++i) {
            int idx = tid + i * 256;
            int r = idx >> 6, c = idx & 63;
            As [r][c] = A[(size_t)(m0 + r) * 128 + k0 + c];
            Bs [r][c] = B[(size_t)(k0 + r) * 1024 + n0 + c];
            Bs2[r][c] = B[(size_t)(k0 + r) * 1024 + 512 + n0 + c];
        }
        __syncthreads();
        #pragma unroll
        for (int kk = 0; kk < 64; ++kk) {
            float a[4], bb[4], bb2[4];
            #pragma unroll
            for (int i = 0; i < 4; ++i) a[i] = As[ty * 4 + i][kk];
            #pragma unroll
            for (int j = 0; j < 4; ++j) { bb[j] = Bs[kk][tx * 4 + j]; bb2[j] = Bs2[kk][tx * 4 + j]; }
            #pragma unroll
            for (int i = 0; i < 4; ++i)
                #pragma unroll
                for (int j = 0; j < 4; ++j) {
                    acc [i][j] = fmaf(a[i], bb [j], acc [i][j]);
                    acc2[i][j] = fmaf(a[i], bb2[j], acc2[i][j]);
                }
        }
        __syncthreads();
    }
    #pragma unroll
    for (int i = 0; i < 4; ++i) {
        int m = m0 + ty * 4 + i;
        #pragma unroll
        for (int j = 0; j < 4; ++j) {
            int n = n0 + tx * 4 + j;
            float av = acc [i][j] + b1[n];
            float gv = acc2[i][j] + b1[512 + n];
            float ge = 0.5f * gv * (1.0f + erff(gv * 0.70710678118654752f));
            C[(size_t)m * 512 + n] = av * ge;
        }
    }
}

// ---------------- Attention: per (r,h) block, one q-row per thread, online softmax -------
__global__ __launch_bounds__(192)
void attn_kernel(const float* __restrict__ Q, const float* __restrict__ K,
                 const float* __restrict__ V, const float* __restrict__ BIAS,
                 const float* __restrict__ G, float* __restrict__ TMP)
{
    __shared__ float kl[NSEQ][DHEAD];
    __shared__ float vl[NSEQ][DHEAD];
    int r = blockIdx.x >> 2;
    int h = blockIdx.x & 3;
    int t = threadIdx.x;
    for (int idx = t; idx < NSEQ * DHEAD; idx += 192) {
        int kc = idx >> 5, e = idx & 31;
        kl[kc][e] = K[((size_t)(r * NSEQ + kc)) * DIM + h * DHEAD + e];
        vl[kc][e] = V[((size_t)(r * NSEQ + kc)) * DIM + h * DHEAD + e];
    }
    __syncthreads();
    float q[DHEAD];
    const float* qp = Q + ((size_t)(r * NSEQ + t)) * DIM + h * DHEAD;
    #pragma unroll
    for (int e = 0; e < DHEAD; ++e) q[e] = qp[e];
    const float* bp = BIAS + (size_t)h * MROWS + (size_t)t * NSEQ;
    float m = -1e30f, s = 0.0f, o[DHEAD] = {};
    for (int kc = 0; kc < NSEQ; ++kc) {
        float d = bp[kc];
        #pragma unroll
        for (int e = 0; e < DHEAD; ++e) d = fmaf(q[e], kl[kc][e], d);
        float mn = fmaxf(m, d);
        float c = __expf(m - mn);
        float p = __expf(d - mn);
        s = s * c + p;
        #pragma unroll
        for (int e = 0; e < DHEAD; ++e) o[e] = o[e] * c + p * vl[kc][e];
        m = mn;
    }
    float inv = 1.0f / s;
    const float* gp = G + ((size_t)(r * NSEQ + t)) * DIM + h * DHEAD;
    float* op = TMP + ((size_t)(r * NSEQ + t)) * DIM + h * DHEAD;
    #pragma unroll
    for (int e = 0; e < DHEAD; ++e) op[e] = o[e] * inv * gp[e];
}

extern "C" void kernel_launch(void* const* d_in, const int* in_sizes, int n_in,
                              void* d_out, int out_size, void* d_ws, size_t ws_size,
                              hipStream_t stream) {
    const float* x     = (const float*)d_in[0];
    const float* lng_o = (const float*)d_in[1];
    const float* lnb_o = (const float*)d_in[2];
    const float* wq_o  = (const float*)d_in[3];
    const float* wkv_o = (const float*)d_in[4];
    const float* wo_o  = (const float*)d_in[5];
    const float* bo_o  = (const float*)d_in[6];
    const float* wg_o  = (const float*)d_in[7];
    const float* bg_o  = (const float*)d_in[8];
    const float* wb_o  = (const float*)d_in[9];
    const float* lng_i = (const float*)d_in[10];
    const float* lnb_i = (const float*)d_in[11];
    const float* wq_i  = (const float*)d_in[12];
    const float* wkv_i = (const float*)d_in[13];
    const float* wo_i  = (const float*)d_in[14];
    const float* bo_i  = (const float*)d_in[15];
    const float* wg_i  = (const float*)d_in[16];
    const float* bg_i  = (const float*)d_in[17];
    const float* wb_i  = (const float*)d_in[18];
    const float* lng_f = (const float*)d_in[19];
    const float* lnb_f = (const float*)d_in[20];
    const float* w1    = (const float*)d_in[21];
    const float* b1    = (const float*)d_in[22];
    const float* w2    = (const float*)d_in[23];
    const float* b2    = (const float*)d_in[24];

    float* ws = (float*)d_ws;
    const size_t T = (size_t)MROWS * DIM; // 4.718M floats
    float* XA    = ws;
    float* X     = XA + T;
    float* Qb    = X + T;
    float* Kb    = Qb + T;
    float* Vb    = Kb + T;
    float* Gb    = Vb + T;
    float* BIASb = Gb + T;         // NH*MROWS
    float* H1    = Qb;             // FFN intermediate (MROWS x 512) reuses Q/K/V/G
    float* TMP   = (float*)d_out;  // o*gates scratch

    const float scale = 0.17677669529663689f; // 32^-0.5
    dim3 g128(MROWS / 64, 2);

    auto stage = [&](const float* xin, float* xout, int trans,
                     const float* lng, const float* lnb, const float* wq,
                     const float* wkv, const float* wo, const float* bo,
                     const float* wg, const float* bg, const float* wb) {
        ln_bias_kernel<<<MROWS / 4, 256, 0, stream>>>(xin, lng, lnb, wb, XA, BIASb, trans);
        gemm_kernel<EPI_SCALE><<<g128, 256, 0, stream>>>(XA, wq, 128, 0, nullptr, nullptr, Qb, 128, 128, scale);
        gemm_kernel<EPI_NONE ><<<g128, 256, 0, stream>>>(XA, wkv, 256, 0,   nullptr, nullptr, Kb, 128, 128, 1.f);
        gemm_kernel<EPI_NONE ><<<g128, 256, 0, stream>>>(XA, wkv, 256, 128, nullptr, nullptr, Vb, 128, 128, 1.f);
        gemm_kernel<EPI_SIG  ><<<g128, 256, 0, stream>>>(XA, wg, 128, 0, bg, nullptr, Gb, 128, 128, 1.f);
        attn_kernel<<<NSEQ * NH, 192, 0, stream>>>(Qb, Kb, Vb, BIASb, Gb, TMP);
        if (trans == 0)
            gemm_kernel<EPI_RES  ><<<g128, 256, 0, stream>>>(TMP, wo, 128, 0, bo, xin, xout, 128, 128, 1.f);
        else
            gemm_kernel<EPI_RES_T><<<g128, 256, 0, stream>>>(TMP, wo, 128, 0, bo, xin, xout, 128, 128, 1.f);
    };

    // stage 1: row attention, x(d_in) -> X
    stage(x, X, 0, lng_o, lnb_o, wq_o, wkv_o, wo_o, bo_o, wg_o, bg_o, wb_o);
    // stage 2: col attention, X -> X (in place; transposed store is a bijection,
    // each element read as residual then written once by the same thread)
    stage(X, X, 1, lng_i, lnb_i, wq_i, wkv_i, wo_i, bo_i, wg_i, bg_i, wb_i);

    // FFN: xn = LN(X); H1 = geglu(xn@w1+b1); out = H1@w2 + b2 + X
    ln_bias_kernel<<<MROWS / 4, 256, 0, stream>>>(X, lng_f, lnb_f, nullptr, XA, nullptr, 0);
    dim3 gg(MROWS / 64, 8);
    gemm_geglu_kernel<<<gg, 256, 0, stream>>>(XA, w1, b1, H1);
    gemm_kernel<EPI_RES><<<g128, 256, 0, stream>>>(H1, w2, 128, 0, b2, X, (float*)d_out, 128, 512, 1.f);
}

// Round 2
// 460.056 us; speedup vs baseline: 2.2463x; 2.2463x over previous
//
#include <hip/hip_runtime.h>
#include <hip/hip_bf16.h>
#include <math.h>

constexpr int NSEQ = 192;
constexpr int DIM  = 128;
constexpr int NH   = 4;
constexpr int DHEAD = 32;
constexpr int MROWS = NSEQ * NSEQ; // 36864

typedef __hip_bfloat16 bf16;
typedef __attribute__((ext_vector_type(8))) short bf16x8;
typedef __attribute__((ext_vector_type(4))) float f32x4;
typedef unsigned int u32;

__device__ __forceinline__ void gload16(const void* g, void* l) {
    __builtin_amdgcn_global_load_lds(
        (const __attribute__((address_space(1))) u32*)g,
        (__attribute__((address_space(3))) u32*)l, 16, 0, 0);
}

// ---------------- Weight prep: f32 -> bf16, transpose to B^T [N][K], fuse/fold ---------
__global__ __launch_bounds__(256)
void convert_weights(const float* __restrict__ wq_o, const float* __restrict__ wkv_o,
                     const float* __restrict__ wg_o,
                     const float* __restrict__ wq_i, const float* __restrict__ wkv_i,
                     const float* __restrict__ wg_i,
                     const float* __restrict__ wo_o, const float* __restrict__ wo_i,
                     const float* __restrict__ w1, const float* __restrict__ b1,
                     const float* __restrict__ w2,
                     bf16* __restrict__ WQKVG_O, bf16* __restrict__ WQKVG_I,
                     bf16* __restrict__ WOT_O, bf16* __restrict__ WOT_I,
                     bf16* __restrict__ W1PT, bf16* __restrict__ W2T,
                     float* __restrict__ B1P)
{
    int idx = blockIdx.x * 256 + threadIdx.x;
    const float scale = 0.17677669529663689f; // 32^-0.5 folded into wq
    if (idx < 131072) {                       // WQKVG_{o,i}: [512][128], rows q|k|v|g
        int s = idx >> 16, i = idx & 65535;
        int r = i >> 7, d = i & 127;
        const float* wq  = s ? wq_i  : wq_o;
        const float* wkv = s ? wkv_i : wkv_o;
        const float* wg  = s ? wg_i  : wg_o;
        float v;
        if (r < 128)      v = wq[d * 128 + r] * scale;
        else if (r < 384) v = wkv[d * 256 + (r - 128)];   // k: cols 0..127, v: 128..255
        else              v = wg[d * 128 + (r - 384)];
        (s ? WQKVG_I : WQKVG_O)[i] = __float2bfloat16(v);
    } else if (idx < 163840) {                // WOT_{o,i}: [128][128] = wo^T
        int i = idx - 131072; int s = i >> 14; i &= 16383;
        int r = i >> 7, d = i & 127;
        (s ? WOT_I : WOT_O)[i] = __float2bfloat16((s ? wo_i : wo_o)[d * 128 + r]);
    } else if (idx < 294912) {                // W1PT: [1024][128], rows 2j=a_j, 2j+1=g_j
        int i = idx - 163840;
        int r = i >> 7, d = i & 127;
        int col = (r & 1) ? 512 + (r >> 1) : (r >> 1);
        W1PT[i] = __float2bfloat16(w1[d * 1024 + col]);
    } else if (idx < 360448) {                // W2T: [128][512] = w2^T
        int i = idx - 294912;
        int n = i >> 9, k = i & 511;
        W2T[i] = __float2bfloat16(w2[k * 128 + n]);
    } else if (idx < 361472) {                // B1P: paired bias
        int r = idx - 360448;
        B1P[r] = b1[(r & 1) ? 512 + (r >> 1) : (r >> 1)];
    }
}

// ---------------- LayerNorm (+ bias-projection, + optional transpose), bf16 out --------
__global__ __launch_bounds__(256)
void ln_bias_kernel(const float* __restrict__ x, const float* __restrict__ g,
                    const float* __restrict__ b, const float* __restrict__ wb,
                    bf16* __restrict__ xa, float* __restrict__ bias, int trans)
{
    int wid  = threadIdx.x >> 6;
    int lane = threadIdx.x & 63;
    int row  = blockIdx.x * 4 + wid;
    const float* xr = x + (size_t)row * DIM;
    float x0 = xr[lane], x1 = xr[lane + 64];
    float s = x0 + x1, sq = x0 * x0 + x1 * x1;
    #pragma unroll
    for (int off = 32; off > 0; off >>= 1) {
        s  += __shfl_down(s, off);
        sq += __shfl_down(sq, off);
    }
    s = __shfl(s, 0); sq = __shfl(sq, 0);
    float mu  = s * (1.0f / 128.0f);
    float var = sq * (1.0f / 128.0f) - mu * mu;
    float rs  = rsqrtf(var + 1e-5f);
    float y0 = (x0 - mu) * rs * g[lane]      + b[lane];
    float y1 = (x1 - mu) * rs * g[lane + 64] + b[lane + 64];
    int orow = row;
    if (trans) { int i = row / NSEQ, j = row % NSEQ; orow = j * NSEQ + i; }
    bf16* yr = xa + (size_t)orow * DIM;
    yr[lane]      = __float2bfloat16(y0);
    yr[lane + 64] = __float2bfloat16(y1);
    if (wb) {
        #pragma unroll
        for (int h = 0; h < NH; ++h) {
            float bh = x0 * wb[lane * NH + h] + x1 * wb[(lane + 64) * NH + h];
            #pragma unroll
            for (int off = 32; off > 0; off >>= 1) bh += __shfl_down(bh, off);
            if (lane == 0) bias[(size_t)h * MROWS + row] = bh;
        }
    }
}

// ---------------- bf16 MFMA GEMM: C[M,N] = A[M,K] @ BT[N,K]^T, fused epilogues ---------
// BM=BN=128, BK=64, 256 threads = 4 waves (2x2), 16x16x32 MFMA, 4x4 frags/wave.
// LDS tiles staged via global_load_lds(16B) with inverse-XOR-swizzled global source;
// ds_read_b128 with matching XOR swizzle (T2): byte ^= (row&7)<<4.
enum { EPI_QKVG = 0, EPI_OUT = 1, EPI_GEGLU = 2, EPI_FF2 = 3 };

template<int EPI>
__global__ __launch_bounds__(256)
void mfma_gemm(const bf16* __restrict__ A, const bf16* __restrict__ BT, int K,
               const float* __restrict__ e_bias,   // bg | bo | b1p | b2
               const float* __restrict__ e_resid,  // -  | xin | -   | X
               float* __restrict__ e_outf,         // Qbase | xout | - | out
               bf16* __restrict__ e_outb,          // -  | -   | H2  | -
               int trans)
{
    __shared__ char sm[32768];                  // As[128][64] | Bs[128][64] bf16
    char* asb = sm;
    char* bsb = sm + 16384;
    int l  = threadIdx.x & 63;
    int w  = threadIdx.x >> 6;
    int wr = w >> 1, wc = w & 1;
    int m0 = blockIdx.x * 128, n0 = blockIdx.y * 128;
    int lr = l >> 3, lc = l & 7;
    int xorc = (lc ^ lr) * 8;                   // inverse-swizzled global k-offset
    int fr = l & 15;
    int fk = (l >> 4) * 16;                     // k byte offset within 64-elem row
    int sw = (l & 7) << 4;                      // read-side XOR swizzle
    f32x4 acc[4][4] = {};

    for (int k0 = 0; k0 < K; k0 += 64) {
        #pragma unroll
        for (int t = 0; t < 4; ++t) {
            int ti = w + t * 4;                 // 16 instrs, 8 rows each
            gload16(A  + (size_t)(m0 + ti * 8 + lr) * K + k0 + xorc, asb + ti * 1024);
            gload16(BT + (size_t)(n0 + ti * 8 + lr) * K + k0 + xorc, bsb + ti * 1024);
        }
        __syncthreads();
        #pragma unroll
        for (int kk = 0; kk < 2; ++kk) {
            bf16x8 af[4], bf_[4];
            #pragma unroll
            for (int i = 0; i < 4; ++i) {
                int ra = wr * 64 + i * 16 + fr;
                int rb = wc * 64 + i * 16 + fr;
                af[i]  = *(const bf16x8*)(asb + ra * 128 + ((kk * 64 + fk) ^ sw));
                bf_[i] = *(const bf16x8*)(bsb + rb * 128 + ((kk * 64 + fk) ^ sw));
            }
            #pragma unroll
            for (int mi = 0; mi < 4; ++mi)
                #pragma unroll
                for (int ni = 0; ni < 4; ++ni)
                    acc[mi][ni] = __builtin_amdgcn_mfma_f32_16x16x32_bf16(
                        af[mi], bf_[ni], acc[mi][ni], 0, 0, 0);
        }
        __syncthreads();
    }

    const size_t T = (size_t)MROWS * DIM;
    #pragma unroll
    for (int mi = 0; mi < 4; ++mi) {
        #pragma unroll
        for (int ni = 0; ni < 4; ++ni) {
            #pragma unroll
            for (int j = 0; j < 4; ++j) {
                int grow = m0 + wr * 64 + mi * 16 + (l >> 4) * 4 + j;
                int gcol = n0 + wc * 64 + ni * 16 + fr;
                float v = acc[mi][ni][j];
                if (EPI == EPI_QKVG) {
                    int seg = gcol >> 7, cc = gcol & 127;
                    if (seg == 3) v = 1.0f / (1.0f + __expf(-(v + e_bias[cc])));
                    e_outf[(size_t)seg * T + (size_t)grow * 128 + cc] = v;
                } else if (EPI == EPI_OUT) {
                    int orow = trans ? ((grow % NSEQ) * NSEQ + grow / NSEQ) : grow;
                    e_outf[(size_t)orow * 128 + gcol] =
                        v + e_bias[gcol] + e_resid[(size_t)orow * 128 + gcol];
                } else if (EPI == EPI_GEGLU) {
                    v += e_bias[gcol];
                    float pg = __shfl_xor(v, 1);
                    if (!(l & 1)) {
                        float ge = 0.5f * pg * (1.0f + erff(pg * 0.70710678118654752f));
                        e_outb[(size_t)grow * 512 + (gcol >> 1)] = __float2bfloat16(v * ge);
                    }
                } else { // EPI_FF2
                    e_outf[(size_t)grow * 128 + gcol] =
                        v + e_bias[gcol] + e_resid[(size_t)grow * 128 + gcol];
                }
            }
        }
    }
}

// ---------------- Attention: per (r,h) block, one q-row per thread, online softmax -----
__global__ __launch_bounds__(192)
void attn_kernel(const float* __restrict__ Q, const float* __restrict__ K,
                 const float* __restrict__ V, const float* __restrict__ BIAS,
                 const float* __restrict__ G, bf16* __restrict__ TMP)
{
    __shared__ float kl[NSEQ][DHEAD];
    __shared__ float vl[NSEQ][DHEAD];
    int r = blockIdx.x >> 2;
    int h = blockIdx.x & 3;
    int t = threadIdx.x;
    for (int idx = t; idx < NSEQ * DHEAD; idx += 192) {
        int kc = idx >> 5, e = idx & 31;
        kl[kc][e] = K[((size_t)(r * NSEQ + kc)) * DIM + h * DHEAD + e];
        vl[kc][e] = V[((size_t)(r * NSEQ + kc)) * DIM + h * DHEAD + e];
    }
    __syncthreads();
    float q[DHEAD];
    const float* qp = Q + ((size_t)(r * NSEQ + t)) * DIM + h * DHEAD;
    #pragma unroll
    for (int e = 0; e < DHEAD; ++e) q[e] = qp[e];
    const float* bp = BIAS + (size_t)h * MROWS + (size_t)t * NSEQ;
    float m = -1e30f, s = 0.0f, o[DHEAD] = {};
    for (int kc = 0; kc < NSEQ; ++kc) {
        float d = bp[kc];
        #pragma unroll
        for (int e = 0; e < DHEAD; ++e) d = fmaf(q[e], kl[kc][e], d);
        float mn = fmaxf(m, d);
        float c = __expf(m - mn);
        float p = __expf(d - mn);
        s = s * c + p;
        #pragma unroll
        for (int e = 0; e < DHEAD; ++e) o[e] = o[e] * c + p * vl[kc][e];
        m = mn;
    }
    float inv = 1.0f / s;
    const float* gp = G + ((size_t)(r * NSEQ + t)) * DIM + h * DHEAD;
    bf16* op = TMP + ((size_t)(r * NSEQ + t)) * DIM + h * DHEAD;
    #pragma unroll
    for (int e = 0; e < DHEAD; ++e) op[e] = __float2bfloat16(o[e] * inv * gp[e]);
}

extern "C" void kernel_launch(void* const* d_in, const int* in_sizes, int n_in,
                              void* d_out, int out_size, void* d_ws, size_t ws_size,
                              hipStream_t stream) {
    const float* x     = (const float*)d_in[0];
    const float* lng_o = (const float*)d_in[1];
    const float* lnb_o = (const float*)d_in[2];
    const float* wq_o  = (const float*)d_in[3];
    const float* wkv_o = (const float*)d_in[4];
    const float* wo_o  = (const float*)d_in[5];
    const float* bo_o  = (const float*)d_in[6];
    const float* wg_o  = (const float*)d_in[7];
    const float* bg_o  = (const float*)d_in[8];
    const float* wb_o  = (const float*)d_in[9];
    const float* lng_i = (const float*)d_in[10];
    const float* lnb_i = (const float*)d_in[11];
    const float* wq_i  = (const float*)d_in[12];
    const float* wkv_i = (const float*)d_in[13];
    const float* wo_i  = (const float*)d_in[14];
    const float* bo_i  = (const float*)d_in[15];
    const float* wg_i  = (const float*)d_in[16];
    const float* bg_i  = (const float*)d_in[17];
    const float* wb_i  = (const float*)d_in[18];
    const float* lng_f = (const float*)d_in[19];
    const float* lnb_f = (const float*)d_in[20];
    const float* w1    = (const float*)d_in[21];
    const float* b1    = (const float*)d_in[22];
    const float* w2    = (const float*)d_in[23];
    const float* b2    = (const float*)d_in[24];

    const size_t T = (size_t)MROWS * DIM;
    char* base = (char*)d_ws;
    bf16*  XA    = (bf16*)base;  base += T * 2;            // bf16 LN output
    float* X     = (float*)base; base += T * 4;            // f32 running residual
    float* Qb    = (float*)base; base += 4 * T * 4;        // Q,K,V,G f32 contiguous
    float* BIASb = (float*)base; base += (size_t)NH * MROWS * 4;
    bf16*  TMP   = (bf16*)base;  base += T * 2;            // o*gates bf16
    bf16*  WQKVG_O = (bf16*)base; base += 512 * 128 * 2;
    bf16*  WQKVG_I = (bf16*)base; base += 512 * 128 * 2;
    bf16*  WOT_O   = (bf16*)base; base += 128 * 128 * 2;
    bf16*  WOT_I   = (bf16*)base; base += 128 * 128 * 2;
    bf16*  W1PT    = (bf16*)base; base += 1024 * 128 * 2;
    bf16*  W2T     = (bf16*)base; base += 128 * 512 * 2;
    float* B1P     = (float*)base; base += 1024 * 4;
    bf16*  H2      = (bf16*)Qb;   // overlay: Q..K region free after stage-2 attn

    convert_weights<<<1412, 256, 0, stream>>>(wq_o, wkv_o, wg_o, wq_i, wkv_i, wg_i,
                                              wo_o, wo_i, w1, b1, w2,
                                              WQKVG_O, WQKVG_I, WOT_O, WOT_I,
                                              W1PT, W2T, B1P);

    dim3 gQKVG(MROWS / 128, 4), gN128(MROWS / 128, 1), gW1(MROWS / 128, 8);

    // ---- stage 1: row attention, x -> X ----
    ln_bias_kernel<<<MROWS / 4, 256, 0, stream>>>(x, lng_o, lnb_o, wb_o, XA, BIASb, 0);
    mfma_gemm<EPI_QKVG><<<gQKVG, 256, 0, stream>>>(XA, WQKVG_O, 128, bg_o, nullptr, Qb, nullptr, 0);
    attn_kernel<<<NSEQ * NH, 192, 0, stream>>>(Qb, Qb + T, Qb + 2 * T, BIASb, Qb + 3 * T, TMP);
    mfma_gemm<EPI_OUT><<<gN128, 256, 0, stream>>>(TMP, WOT_O, 128, bo_o, x, X, nullptr, 0);

    // ---- stage 2: col attention, X -> X (transposed store is a bijection) ----
    ln_bias_kernel<<<MROWS / 4, 256, 0, stream>>>(X, lng_i, lnb_i, wb_i, XA, BIASb, 1);
    mfma_gemm<EPI_QKVG><<<gQKVG, 256, 0, stream>>>(XA, WQKVG_I, 128, bg_i, nullptr, Qb, nullptr, 0);
    attn_kernel<<<NSEQ * NH, 192, 0, stream>>>(Qb, Qb + T, Qb + 2 * T, BIASb, Qb + 3 * T, TMP);
    mfma_gemm<EPI_OUT><<<gN128, 256, 0, stream>>>(TMP, WOT_I, 128, bo_i, X, X, nullptr, 1);

    // ---- FFN: xn = LN(X); H2 = geglu(xn@w1p+b1p); out = H2@w2 + b2 + X ----
    ln_bias_kernel<<<MROWS / 4, 256, 0, stream>>>(X, lng_f, lnb_f, nullptr, XA, nullptr, 0);
    mfma_gemm<EPI_GEGLU><<<gW1, 256, 0, stream>>>(XA, W1PT, 128, B1P, nullptr, nullptr, H2, 0);
    mfma_gemm<EPI_FF2><<<gN128, 256, 0, stream>>>(H2, W2T, 512, b2, X, (float*)d_out, nullptr, 0);
}

// Round 3
// 267.215 us; speedup vs baseline: 3.8674x; 1.7217x over previous
//
#include <hip/hip_runtime.h>
#include <hip/hip_bf16.h>
#include <math.h>

constexpr int NSEQ = 192;
constexpr int DIM  = 128;
constexpr int NH   = 4;
constexpr int DHEAD = 32;
constexpr int MROWS = NSEQ * NSEQ; // 36864

typedef __hip_bfloat16 bf16;
typedef __attribute__((ext_vector_type(8))) short bf16x8;
typedef __attribute__((ext_vector_type(4))) float f32x4;
typedef unsigned int u32;

__device__ __forceinline__ void gload16(const void* g, void* l) {
    __builtin_amdgcn_global_load_lds(
        (const __attribute__((address_space(1))) u32*)g,
        (__attribute__((address_space(3))) u32*)l, 16, 0, 0);
}

__device__ __forceinline__ short f2bs(float f) {
    __hip_bfloat16 h = __float2bfloat16(f);
    return *(short*)&h;
}

// ---------------- Weight prep: f32 -> bf16, transpose to B^T [N][K], fuse/fold ---------
__global__ __launch_bounds__(256)
void convert_weights(const float* __restrict__ wq_o, const float* __restrict__ wkv_o,
                     const float* __restrict__ wg_o,
                     const float* __restrict__ wq_i, const float* __restrict__ wkv_i,
                     const float* __restrict__ wg_i,
                     const float* __restrict__ wo_o, const float* __restrict__ wo_i,
                     const float* __restrict__ w1, const float* __restrict__ b1,
                     const float* __restrict__ w2,
                     bf16* __restrict__ WQKVG_O, bf16* __restrict__ WQKVG_I,
                     bf16* __restrict__ WOT_O, bf16* __restrict__ WOT_I,
                     bf16* __restrict__ W1PT, bf16* __restrict__ W2T,
                     float* __restrict__ B1P)
{
    int idx = blockIdx.x * 256 + threadIdx.x;
    const float scale = 0.17677669529663689f; // 32^-0.5 folded into wq
    if (idx < 131072) {                       // WQKVG_{o,i}: [512][128], rows q|k|v|g
        int s = idx >> 16, i = idx & 65535;
        int r = i >> 7, d = i & 127;
        const float* wq  = s ? wq_i  : wq_o;
        const float* wkv = s ? wkv_i : wkv_o;
        const float* wg  = s ? wg_i  : wg_o;
        float v;
        if (r < 128)      v = wq[d * 128 + r] * scale;
        else if (r < 384) v = wkv[d * 256 + (r - 128)];   // k: cols 0..127, v: 128..255
        else              v = wg[d * 128 + (r - 384)];
        (s ? WQKVG_I : WQKVG_O)[i] = __float2bfloat16(v);
    } else if (idx < 163840) {                // WOT_{o,i}: [128][128] = wo^T
        int i = idx - 131072; int s = i >> 14; i &= 16383;
        int r = i >> 7, d = i & 127;
        (s ? WOT_I : WOT_O)[i] = __float2bfloat16((s ? wo_i : wo_o)[d * 128 + r]);
    } else if (idx < 294912) {                // W1PT: [1024][128], rows 2j=a_j, 2j+1=g_j
        int i = idx - 163840;
        int r = i >> 7, d = i & 127;
        int col = (r & 1) ? 512 + (r >> 1) : (r >> 1);
        W1PT[i] = __float2bfloat16(w1[d * 1024 + col]);
    } else if (idx < 360448) {                // W2T: [128][512] = w2^T
        int i = idx - 294912;
        int n = i >> 9, k = i & 511;
        W2T[i] = __float2bfloat16(w2[k * 128 + n]);
    } else if (idx < 361472) {                // B1P: paired bias
        int r = idx - 360448;
        B1P[r] = b1[(r & 1) ? 512 + (r >> 1) : (r >> 1)];
    }
}

// ---------------- LayerNorm (+ bias-projection, + optional transpose), bf16 out --------
__global__ __launch_bounds__(256)
void ln_bias_kernel(const float* __restrict__ x, const float* __restrict__ g,
                    const float* __restrict__ b, const float* __restrict__ wb,
                    bf16* __restrict__ xa, float* __restrict__ bias, int trans)
{
    int wid  = threadIdx.x >> 6;
    int lane = threadIdx.x & 63;
    int row  = blockIdx.x * 4 + wid;
    const float* xr = x + (size_t)row * DIM;
    float x0 = xr[lane], x1 = xr[lane + 64];
    float s = x0 + x1, sq = x0 * x0 + x1 * x1;
    #pragma unroll
    for (int off = 32; off > 0; off >>= 1) {
        s  += __shfl_down(s, off);
        sq += __shfl_down(sq, off);
    }
    s = __shfl(s, 0); sq = __shfl(sq, 0);
    float mu  = s * (1.0f / 128.0f);
    float var = sq * (1.0f / 128.0f) - mu * mu;
    float rs  = rsqrtf(var + 1e-5f);
    float y0 = (x0 - mu) * rs * g[lane]      + b[lane];
    float y1 = (x1 - mu) * rs * g[lane + 64] + b[lane + 64];
    int orow = row;
    if (trans) { int i = row / NSEQ, j = row % NSEQ; orow = j * NSEQ + i; }
    bf16* yr = xa + (size_t)orow * DIM;
    yr[lane]      = __float2bfloat16(y0);
    yr[lane + 64] = __float2bfloat16(y1);
    if (wb) {
        #pragma unroll
        for (int h = 0; h < NH; ++h) {
            float bh = x0 * wb[lane * NH + h] + x1 * wb[(lane + 64) * NH + h];
            #pragma unroll
            for (int off = 32; off > 0; off >>= 1) bh += __shfl_down(bh, off);
            if (lane == 0) bias[(size_t)h * MROWS + row] = bh;
        }
    }
}

// ---------------- bf16 MFMA GEMM: C[M,N] = A[M,K] @ BT[N,K]^T, fused epilogues ---------
enum { EPI_QKVG = 0, EPI_OUT = 1, EPI_GEGLU = 2, EPI_FF2 = 3 };

template<int EPI>
__global__ __launch_bounds__(256)
void mfma_gemm(const bf16* __restrict__ A, const bf16* __restrict__ BT, int K,
               const float* __restrict__ e_bias,   // bg | bo | b1p | b2
               const float* __restrict__ e_resid,  // -  | xin | -   | X
               float* __restrict__ e_outf,         // G  | xout | -  | out
               bf16* __restrict__ e_outb,          // QKV| -   | H2  | -
               int trans)
{
    __shared__ char sm[32768];                  // As[128][64] | Bs[128][64] bf16
    char* asb = sm;
    char* bsb = sm + 16384;
    int l  = threadIdx.x & 63;
    int w  = threadIdx.x >> 6;
    int wr = w >> 1, wc = w & 1;
    int m0 = blockIdx.x * 128, n0 = blockIdx.y * 128;
    int lr = l >> 3, lc = l & 7;
    int xorc = (lc ^ lr) * 8;                   // inverse-swizzled global k-offset
    int fr = l & 15;
    int fk = (l >> 4) * 16;                     // k byte offset within 64-elem row
    int sw = (l & 7) << 4;                      // read-side XOR swizzle
    f32x4 acc[4][4] = {};

    for (int k0 = 0; k0 < K; k0 += 64) {
        #pragma unroll
        for (int t = 0; t < 4; ++t) {
            int ti = w + t * 4;                 // 16 instrs, 8 rows each
            gload16(A  + (size_t)(m0 + ti * 8 + lr) * K + k0 + xorc, asb + ti * 1024);
            gload16(BT + (size_t)(n0 + ti * 8 + lr) * K + k0 + xorc, bsb + ti * 1024);
        }
        __syncthreads();
        #pragma unroll
        for (int kk = 0; kk < 2; ++kk) {
            bf16x8 af[4], bf_[4];
            #pragma unroll
            for (int i = 0; i < 4; ++i) {
                int ra = wr * 64 + i * 16 + fr;
                int rb = wc * 64 + i * 16 + fr;
                af[i]  = *(const bf16x8*)(asb + ra * 128 + ((kk * 64 + fk) ^ sw));
                bf_[i] = *(const bf16x8*)(bsb + rb * 128 + ((kk * 64 + fk) ^ sw));
            }
            #pragma unroll
            for (int mi = 0; mi < 4; ++mi)
                #pragma unroll
                for (int ni = 0; ni < 4; ++ni)
                    acc[mi][ni] = __builtin_amdgcn_mfma_f32_16x16x32_bf16(
                        af[mi], bf_[ni], acc[mi][ni], 0, 0, 0);
        }
        __syncthreads();
    }

    #pragma unroll
    for (int mi = 0; mi < 4; ++mi) {
        #pragma unroll
        for (int ni = 0; ni < 4; ++ni) {
            #pragma unroll
            for (int j = 0; j < 4; ++j) {
                int grow = m0 + wr * 64 + mi * 16 + (l >> 4) * 4 + j;
                int gcol = n0 + wc * 64 + ni * 16 + fr;
                float v = acc[mi][ni][j];
                if (EPI == EPI_QKVG) {
                    int seg = gcol >> 7, cc = gcol & 127;
                    if (seg == 3) {
                        e_outf[(size_t)grow * 128 + cc] =
                            1.0f / (1.0f + __expf(-(v + e_bias[cc])));
                    } else {
                        int hh = cc >> 5, ee = cc & 31;
                        e_outb[((size_t)seg * NH + hh) * ((size_t)MROWS * DHEAD)
                               + (size_t)grow * DHEAD + ee] = __float2bfloat16(v);
                    }
                } else if (EPI == EPI_OUT) {
                    int orow = trans ? ((grow % NSEQ) * NSEQ + grow / NSEQ) : grow;
                    e_outf[(size_t)orow * 128 + gcol] =
                        v + e_bias[gcol] + e_resid[(size_t)orow * 128 + gcol];
                } else if (EPI == EPI_GEGLU) {
                    v += e_bias[gcol];
                    float pg = __shfl_xor(v, 1);
                    if (!(l & 1)) {
                        float ge = 0.5f * pg * (1.0f + erff(pg * 0.70710678118654752f));
                        e_outb[(size_t)grow * 512 + (gcol >> 1)] = __float2bfloat16(v * ge);
                    }
                } else { // EPI_FF2
                    e_outf[(size_t)grow * 128 + gcol] =
                        v + e_bias[gcol] + e_resid[(size_t)grow * 128 + gcol];
                }
            }
        }
    }
}

// ---------------- MFMA flash attention: block=(h,r), 4 waves x 48 q-rows ---------------
// S^T = mfma(K-tile, Q^T-tile): lane holds q=lane&15, k=(lane>>4)*4+j -> lane-local
// softmax rows. PV: O^T = mfma(V^T-tile, P^T) with V^T staged in LDS k-permuted so
// both operands use slot pi(g,s); P^T frag == S^T D-layout (slot match by f(k)).
__global__ __launch_bounds__(256)
void attn_mfma_kernel(const bf16* __restrict__ Qh, const bf16* __restrict__ Kh,
                      const bf16* __restrict__ Vh, const float* __restrict__ BIAS,
                      const float* __restrict__ G, bf16* __restrict__ TMP)
{
    __shared__ unsigned short vtp[32][200];   // V^T permuted, row stride 400B (16B mult)
    int h = blockIdx.x / NSEQ;
    int r = blockIdx.x % NSEQ;
    int t = threadIdx.x;
    int l = t & 63;
    int w = t >> 6;

    // ---- stage V^T permuted: vtp[e][sup*32 + f(k')] = V[k][e] ----
    const bf16* vbase = Vh + ((size_t)h * MROWS + (size_t)r * NSEQ) * DHEAD;
    #pragma unroll
    for (int i = 0; i < 6; ++i) {
        int q4 = t + i * 256;                 // 1536 quads
        int k = q4 >> 3, e0 = (q4 & 7) * 4;
        uint2 v = *(const uint2*)(vbase + (size_t)k * DHEAD + e0);
        int kk = k & 31, sup = k >> 5;
        int col = sup * 32 + ((kk & 15) >> 2) * 8 + (kk & 3) + ((kk >> 4) << 2);
        const unsigned short* vs = (const unsigned short*)&v;
        #pragma unroll
        for (int j = 0; j < 4; ++j) vtp[e0 + j][col] = vs[j];
    }
    __syncthreads();

    int fr = l & 15, g = l >> 4;
    int q0 = w * 48;
    const bf16*  qbase = Qh + ((size_t)h * MROWS + (size_t)r * NSEQ) * DHEAD;
    const bf16*  kbase = Kh + ((size_t)h * MROWS + (size_t)r * NSEQ) * DHEAD;
    const float* bbase = BIAS + (size_t)h * MROWS;

    bf16x8 qf[3];
    #pragma unroll
    for (int i = 0; i < 3; ++i)
        qf[i] = *(const bf16x8*)(qbase + (size_t)(q0 + i * 16 + fr) * DHEAD + g * 8);

    f32x4 ot[3][2] = {};
    float m_[3] = {-1e30f, -1e30f, -1e30f};
    float s_[3] = {};

    for (int sup = 0; sup < 6; ++sup) {
        bf16x8 kf0 = *(const bf16x8*)(kbase + (size_t)(sup * 32 + fr) * DHEAD + g * 8);
        bf16x8 kf1 = *(const bf16x8*)(kbase + (size_t)(sup * 32 + 16 + fr) * DHEAD + g * 8);
        bf16x8 pb[3];
        #pragma unroll
        for (int qt = 0; qt < 3; ++qt) {
            f32x4 z = {};
            f32x4 s0 = __builtin_amdgcn_mfma_f32_16x16x32_bf16(kf0, qf[qt], z, 0, 0, 0);
            f32x4 s1 = __builtin_amdgcn_mfma_f32_16x16x32_bf16(kf1, qf[qt], z, 0, 0, 0);
            const float* bp = bbase + (size_t)(q0 + qt * 16 + fr) * NSEQ + sup * 32 + g * 4;
            float4 b0 = *(const float4*)bp;
            float4 b1 = *(const float4*)(bp + 16);
            s0[0] += b0.x; s0[1] += b0.y; s0[2] += b0.z; s0[3] += b0.w;
            s1[0] += b1.x; s1[1] += b1.y; s1[2] += b1.z; s1[3] += b1.w;
            float tmax = fmaxf(fmaxf(fmaxf(s0[0], s0[1]), fmaxf(s0[2], s0[3])),
                               fmaxf(fmaxf(s1[0], s1[1]), fmaxf(s1[2], s1[3])));
            tmax = fmaxf(tmax, __shfl_xor(tmax, 16));
            tmax = fmaxf(tmax, __shfl_xor(tmax, 32));
            if (__any(tmax > m_[qt] + 8.0f)) {       // defer-max (T13)
                float mn = fmaxf(m_[qt], tmax);
                float c = __expf(m_[qt] - mn);
                s_[qt] *= c; ot[qt][0] *= c; ot[qt][1] *= c;
                m_[qt] = mn;
            }
            float p[8];
            #pragma unroll
            for (int j = 0; j < 4; ++j) p[j]     = __expf(s0[j] - m_[qt]);
            #pragma unroll
            for (int j = 0; j < 4; ++j) p[4 + j] = __expf(s1[j] - m_[qt]);
            s_[qt] += ((p[0] + p[1]) + (p[2] + p[3])) + ((p[4] + p[5]) + (p[6] + p[7]));
            bf16x8 pk;
            #pragma unroll
            for (int j = 0; j < 8; ++j) pk[j] = f2bs(p[j]);
            pb[qt] = pk;
        }
        #pragma unroll
        for (int et = 0; et < 2; ++et) {
            bf16x8 vf = *(const bf16x8*)(&vtp[et * 16 + fr][sup * 32 + g * 8]);
            #pragma unroll
            for (int qt = 0; qt < 3; ++qt)
                ot[qt][et] = __builtin_amdgcn_mfma_f32_16x16x32_bf16(vf, pb[qt], ot[qt][et], 0, 0, 0);
        }
    }

    // ---- epilogue: O = O^T/s * gate, bf16 store ----
    #pragma unroll
    for (int qt = 0; qt < 3; ++qt) {
        float sq = s_[qt];
        sq += __shfl_xor(sq, 16);
        sq += __shfl_xor(sq, 32);
        float inv = 1.0f / sq;
        int q = q0 + qt * 16 + fr;
        size_t row = (size_t)r * NSEQ + q;
        #pragma unroll
        for (int et = 0; et < 2; ++et) {
            int e0 = h * DHEAD + et * 16 + g * 4;
            float4 gv = *(const float4*)(G + row * DIM + e0);
            short o4[4];
            o4[0] = f2bs(ot[qt][et][0] * inv * gv.x);
            o4[1] = f2bs(ot[qt][et][1] * inv * gv.y);
            o4[2] = f2bs(ot[qt][et][2] * inv * gv.z);
            o4[3] = f2bs(ot[qt][et][3] * inv * gv.w);
            *(uint2*)(TMP + row * DIM + e0) = *(uint2*)o4;
        }
    }
}

extern "C" void kernel_launch(void* const* d_in, const int* in_sizes, int n_in,
                              void* d_out, int out_size, void* d_ws, size_t ws_size,
                              hipStream_t stream) {
    const float* x     = (const float*)d_in[0];
    const float* lng_o = (const float*)d_in[1];
    const float* lnb_o = (const float*)d_in[2];
    const float* wq_o  = (const float*)d_in[3];
    const float* wkv_o = (const float*)d_in[4];
    const float* wo_o  = (const float*)d_in[5];
    const float* bo_o  = (const float*)d_in[6];
    const float* wg_o  = (const float*)d_in[7];
    const float* bg_o  = (const float*)d_in[8];
    const float* wb_o  = (const float*)d_in[9];
    const float* lng_i = (const float*)d_in[10];
    const float* lnb_i = (const float*)d_in[11];
    const float* wq_i  = (const float*)d_in[12];
    const float* wkv_i = (const float*)d_in[13];
    const float* wo_i  = (const float*)d_in[14];
    const float* bo_i  = (const float*)d_in[15];
    const float* wg_i  = (const float*)d_in[16];
    const float* bg_i  = (const float*)d_in[17];
    const float* wb_i  = (const float*)d_in[18];
    const float* lng_f = (const float*)d_in[19];
    const float* lnb_f = (const float*)d_in[20];
    const float* w1    = (const float*)d_in[21];
    const float* b1    = (const float*)d_in[22];
    const float* w2    = (const float*)d_in[23];
    const float* b2    = (const float*)d_in[24];

    const size_t T = (size_t)MROWS * DIM;
    char* base = (char*)d_ws;
    bf16*  XA    = (bf16*)base;  base += T * 2;            // bf16 LN output
    float* X     = (float*)base; base += T * 4;            // f32 running residual
    bf16*  QKVb  = (bf16*)base;  base += 3 * T * 2;        // Q,K,V bf16 [3][4][MROWS][32]
    float* Gf    = (float*)base; base += T * 4;            // gate f32 [MROWS][128]
    float* BIASb = (float*)base; base += (size_t)NH * MROWS * 4;
    bf16*  TMP   = (bf16*)base;  base += T * 2;            // o*gates bf16
    bf16*  WQKVG_O = (bf16*)base; base += 512 * 128 * 2;
    bf16*  WQKVG_I = (bf16*)base; base += 512 * 128 * 2;
    bf16*  WOT_O   = (bf16*)base; base += 128 * 128 * 2;
    bf16*  WOT_I   = (bf16*)base; base += 128 * 128 * 2;
    bf16*  W1PT    = (bf16*)base; base += 1024 * 128 * 2;
    bf16*  W2T     = (bf16*)base; base += 128 * 512 * 2;
    float* B1P     = (float*)base; base += 1024 * 4;
    bf16*  H2      = (bf16*)QKVb;  // overlay: QKVb+Gf (47MB) free during FFN, H2 = 37.7MB
    bf16*  Qhp = QKVb;
    bf16*  Khp = QKVb + T;
    bf16*  Vhp = QKVb + 2 * T;

    convert_weights<<<1412, 256, 0, stream>>>(wq_o, wkv_o, wg_o, wq_i, wkv_i, wg_i,
                                              wo_o, wo_i, w1, b1, w2,
                                              WQKVG_O, WQKVG_I, WOT_O, WOT_I,
                                              W1PT, W2T, B1P);

    dim3 gQKVG(MROWS / 128, 4), gN128(MROWS / 128, 1), gW1(MROWS / 128, 8);

    // ---- stage 1: row attention, x -> X ----
    ln_bias_kernel<<<MROWS / 4, 256, 0, stream>>>(x, lng_o, lnb_o, wb_o, XA, BIASb, 0);
    mfma_gemm<EPI_QKVG><<<gQKVG, 256, 0, stream>>>(XA, WQKVG_O, 128, bg_o, nullptr, Gf, QKVb, 0);
    attn_mfma_kernel<<<NSEQ * NH, 256, 0, stream>>>(Qhp, Khp, Vhp, BIASb, Gf, TMP);
    mfma_gemm<EPI_OUT><<<gN128, 256, 0, stream>>>(TMP, WOT_O, 128, bo_o, x, X, nullptr, 0);

    // ---- stage 2: col attention, X -> X (transposed store is a bijection) ----
    ln_bias_kernel<<<MROWS / 4, 256, 0, stream>>>(X, lng_i, lnb_i, wb_i, XA, BIASb, 1);
    mfma_gemm<EPI_QKVG><<<gQKVG, 256, 0, stream>>>(XA, WQKVG_I, 128, bg_i, nullptr, Gf, QKVb, 0);
    attn_mfma_kernel<<<NSEQ * NH, 256, 0, stream>>>(Qhp, Khp, Vhp, BIASb, Gf, TMP);
    mfma_gemm<EPI_OUT><<<gN128, 256, 0, stream>>>(TMP, WOT_I, 128, bo_i, X, X, nullptr, 1);

    // ---- FFN: xn = LN(X); H2 = geglu(xn@w1p+b1p); out = H2@w2 + b2 + X ----
    ln_bias_kernel<<<MROWS / 4, 256, 0, stream>>>(X, lng_f, lnb_f, nullptr, XA, nullptr, 0);
    mfma_gemm<EPI_GEGLU><<<gW1, 256, 0, stream>>>(XA, W1PT, 128, B1P, nullptr, nullptr, H2, 0);
    mfma_gemm<EPI_FF2><<<gN128, 256, 0, stream>>>(H2, W2T, 512, b2, X, (float*)d_out, nullptr, 0);
}

// Round 4
// 241.001 us; speedup vs baseline: 4.2881x; 1.1088x over previous
//
#include <hip/hip_runtime.h>
#include <hip/hip_bf16.h>
#include <math.h>

constexpr int NSEQ = 192;
constexpr int DIM  = 128;
constexpr int NH   = 4;
constexpr int DHEAD = 32;
constexpr int MROWS = NSEQ * NSEQ; // 36864

typedef __hip_bfloat16 bf16;
typedef __attribute__((ext_vector_type(8))) short bf16x8;
typedef __attribute__((ext_vector_type(4))) float f32x4;
typedef unsigned int u32;

__device__ __forceinline__ void gload16(const void* g, void* l) {
    __builtin_amdgcn_global_load_lds(
        (const __attribute__((address_space(1))) u32*)g,
        (__attribute__((address_space(3))) u32*)l, 16, 0, 0);
}

__device__ __forceinline__ short f2bs(float f) {
    __hip_bfloat16 h = __float2bfloat16(f);
    return *(short*)&h;
}
__device__ __forceinline__ float bs2f(unsigned short s) {
    return __uint_as_float(((u32)s) << 16);
}

// ---------------- Weight prep: f32 -> bf16, transpose to B^T [N][K], fuse/fold ---------
__global__ __launch_bounds__(256)
void convert_weights(const float* __restrict__ wq_o, const float* __restrict__ wkv_o,
                     const float* __restrict__ wg_o,
                     const float* __restrict__ wq_i, const float* __restrict__ wkv_i,
                     const float* __restrict__ wg_i,
                     const float* __restrict__ wo_o, const float* __restrict__ wo_i,
                     const float* __restrict__ w1, const float* __restrict__ b1,
                     const float* __restrict__ w2,
                     bf16* __restrict__ WQKVG_O, bf16* __restrict__ WQKVG_I,
                     bf16* __restrict__ WOT_O, bf16* __restrict__ WOT_I,
                     bf16* __restrict__ W1PT, bf16* __restrict__ W2T,
                     float* __restrict__ B1P)
{
    int idx = blockIdx.x * 256 + threadIdx.x;
    const float scale = 0.17677669529663689f; // 32^-0.5 folded into wq
    if (idx < 131072) {                       // WQKVG_{o,i}: [512][128], rows q|k|v|g
        int s = idx >> 16, i = idx & 65535;
        int r = i >> 7, d = i & 127;
        const float* wq  = s ? wq_i  : wq_o;
        const float* wkv = s ? wkv_i : wkv_o;
        const float* wg  = s ? wg_i  : wg_o;
        float v;
        if (r < 128)      v = wq[d * 128 + r] * scale;
        else if (r < 384) v = wkv[d * 256 + (r - 128)];   // k: cols 0..127, v: 128..255
        else              v = wg[d * 128 + (r - 384)];
        (s ? WQKVG_I : WQKVG_O)[i] = __float2bfloat16(v);
    } else if (idx < 163840) {                // WOT_{o,i}: [128][128] = wo^T
        int i = idx - 131072; int s = i >> 14; i &= 16383;
        int r = i >> 7, d = i & 127;
        (s ? WOT_I : WOT_O)[i] = __float2bfloat16((s ? wo_i : wo_o)[d * 128 + r]);
    } else if (idx < 294912) {                // W1PT: [1024][128], rows 2j=a_j, 2j+1=g_j
        int i = idx - 163840;
        int r = i >> 7, d = i & 127;
        int col = (r & 1) ? 512 + (r >> 1) : (r >> 1);
        W1PT[i] = __float2bfloat16(w1[d * 1024 + col]);
    } else if (idx < 360448) {                // W2T: [128][512] = w2^T
        int i = idx - 294912;
        int n = i >> 9, k = i & 511;
        W2T[i] = __float2bfloat16(w2[k * 128 + n]);
    } else if (idx < 361472) {                // B1P: paired bias
        int r = idx - 360448;
        B1P[r] = b1[(r & 1) ? 512 + (r >> 1) : (r >> 1)];
    }
}

// ---------------- LayerNorm (+ bias-projection, + optional transpose), bf16 out --------
__global__ __launch_bounds__(256)
void ln_bias_kernel(const float* __restrict__ x, const float* __restrict__ g,
                    const float* __restrict__ b, const float* __restrict__ wb,
                    bf16* __restrict__ xa, float* __restrict__ bias, int trans)
{
    int wid  = threadIdx.x >> 6;
    int lane = threadIdx.x & 63;
    int row  = blockIdx.x * 4 + wid;
    const float* xr = x + (size_t)row * DIM;
    float x0 = xr[lane], x1 = xr[lane + 64];
    float s = x0 + x1, sq = x0 * x0 + x1 * x1;
    #pragma unroll
    for (int off = 32; off > 0; off >>= 1) {
        s  += __shfl_down(s, off);
        sq += __shfl_down(sq, off);
    }
    s = __shfl(s, 0); sq = __shfl(sq, 0);
    float mu  = s * (1.0f / 128.0f);
    float var = sq * (1.0f / 128.0f) - mu * mu;
    float rs  = rsqrtf(var + 1e-5f);
    float y0 = (x0 - mu) * rs * g[lane]      + b[lane];
    float y1 = (x1 - mu) * rs * g[lane + 64] + b[lane + 64];
    int orow = row;
    if (trans) { int i = row / NSEQ, j = row % NSEQ; orow = j * NSEQ + i; }
    bf16* yr = xa + (size_t)orow * DIM;
    yr[lane]      = __float2bfloat16(y0);
    yr[lane + 64] = __float2bfloat16(y1);
    if (wb) {
        #pragma unroll
        for (int h = 0; h < NH; ++h) {
            float bh = x0 * wb[lane * NH + h] + x1 * wb[(lane + 64) * NH + h];
            #pragma unroll
            for (int off = 32; off > 0; off >>= 1) bh += __shfl_down(bh, off);
            if (lane == 0) bias[(size_t)h * MROWS + row] = bh;
        }
    }
}

// ---------------- bf16 MFMA GEMM, BK=128 single-stage, LDS-repacked epilogues ----------
// BM x 128 tile, 4 waves (2x2), 16x16x32 MFMA. Staging: global_load_lds 16B with
// pre-swizzled source atoms (atom ^= row&7); reads XOR the same key -> 0 conflicts.
// Epilogue: acc -> f32 LDS [BM][128] with atom rotation (atom+row)&31 (bank floor),
// readback 16 cols/row per thread -> coalesced vector stores.
enum { EPI_QKVG = 0, EPI_OUT = 1, EPI_GEGLU = 2, EPI_FF2 = 3 };

template<int EPI, int BM, int K>
__global__ __launch_bounds__(256)
void mfma_gemm(const bf16* __restrict__ A, const bf16* __restrict__ BT,
               const float* __restrict__ e_bias,   // bg | bo | b1p | b2
               const float* __restrict__ e_resid,  // -  | xin | -   | X
               float* __restrict__ e_outf,         // -  | xout| -   | out
               bf16* __restrict__ e_outb,          // QKV| -   | H2  | -
               bf16* __restrict__ e_outb2,         // Gb | -   | -   | -
               int trans)
{
    constexpr int MREP = BM / 32;
    constexpr int ABYTES = BM * 256;
    constexpr int STAGEB = ABYTES + 32768;
    constexpr int EPIB = BM * 512;
    constexpr int LDSB = STAGEB > EPIB ? STAGEB : EPIB;
    __shared__ char sm[LDSB];
    char* asb = sm;
    char* bsb = sm + ABYTES;
    float* eb = (float*)sm;

    int tid = threadIdx.x;
    int l = tid & 63, w = tid >> 6;
    int wr = w >> 1, wc = w & 1;
    int m0 = blockIdx.x * BM, n0 = blockIdx.y * 128;
    int fr = l & 15, g = l >> 4;
    int srow  = tid >> 4;                      // 0..15 within a 16-row round
    int satom = (tid & 15) ^ (srow & 7);       // pre-swizzled source atom

    f32x4 acc[MREP][4] = {};

    for (int k0 = 0; k0 < K; k0 += 128) {
        #pragma unroll
        for (int i = 0; i < BM / 16; ++i)
            gload16(A + (size_t)(m0 + i * 16 + srow) * K + k0 + satom * 8,
                    asb + i * 4096 + w * 1024);
        #pragma unroll
        for (int i = 0; i < 8; ++i)
            gload16(BT + (size_t)(n0 + i * 16 + srow) * K + k0 + satom * 8,
                    bsb + i * 4096 + w * 1024);
        __syncthreads();
        #pragma unroll
        for (int kk = 0; kk < 4; ++kk) {
            bf16x8 af[MREP], bfr[4];
            #pragma unroll
            for (int mi = 0; mi < MREP; ++mi) {
                int r = wr * (BM / 2) + mi * 16 + fr;
                af[mi] = *(const bf16x8*)(asb + r * 256 + ((kk * 64 + g * 16) ^ ((r & 7) << 4)));
            }
            #pragma unroll
            for (int ni = 0; ni < 4; ++ni) {
                int r = wc * 64 + ni * 16 + fr;
                bfr[ni] = *(const bf16x8*)(bsb + r * 256 + ((kk * 64 + g * 16) ^ ((r & 7) << 4)));
            }
            #pragma unroll
            for (int mi = 0; mi < MREP; ++mi)
                #pragma unroll
                for (int ni = 0; ni < 4; ++ni)
                    acc[mi][ni] = __builtin_amdgcn_mfma_f32_16x16x32_bf16(
                        af[mi], bfr[ni], acc[mi][ni], 0, 0, 0);
        }
        __syncthreads();
    }

    // ---- acc -> LDS f32 [BM][128], atom-rotated ----
    #pragma unroll
    for (int mi = 0; mi < MREP; ++mi)
        #pragma unroll
        for (int ni = 0; ni < 4; ++ni)
            #pragma unroll
            for (int j = 0; j < 4; ++j) {
                int rl = wr * (BM / 2) + mi * 16 + g * 4 + j;
                int cl = wc * 64 + ni * 16 + fr;
                int a  = ((cl >> 2) + rl) & 31;
                eb[rl * 128 + (a << 2) + (cl & 3)] = acc[mi][ni][j];
            }
    __syncthreads();

    // ---- readback: each thread owns 16 consecutive cols of a row ----
    #pragma unroll
    for (int p = 0; p < BM / 32; ++p) {
        int c = tid + p * 256;
        int row = c >> 3;
        int ch = c & 7;
        int grow = m0 + row;
        int gc0 = ch * 16;
        float v[16];
        #pragma unroll
        for (int q = 0; q < 4; ++q) {
            f32x4 t4 = *(const f32x4*)&eb[row * 128 + (((ch * 4 + q + row) & 31) << 2)];
            v[q * 4 + 0] = t4[0]; v[q * 4 + 1] = t4[1];
            v[q * 4 + 2] = t4[2]; v[q * 4 + 3] = t4[3];
        }
        if (EPI == EPI_QKVG) {
            int seg = blockIdx.y;
            short o16[16];
            if (seg < 3) {
                #pragma unroll
                for (int i = 0; i < 16; ++i) o16[i] = f2bs(v[i]);
                int h = gc0 >> 5, e0 = gc0 & 31;
                bf16* dst = e_outb + ((size_t)(seg * NH + h) * MROWS + grow) * DHEAD + e0;
                *(uint4*)dst = *(uint4*)o16;
                *(uint4*)(dst + 8) = *(uint4*)(o16 + 8);
            } else {
                #pragma unroll
                for (int i = 0; i < 16; ++i)
                    o16[i] = f2bs(1.0f / (1.0f + __expf(-(v[i] + e_bias[gc0 + i]))));
                bf16* dst = e_outb2 + (size_t)grow * DIM + gc0;
                *(uint4*)dst = *(uint4*)o16;
                *(uint4*)(dst + 8) = *(uint4*)(o16 + 8);
            }
        } else if (EPI == EPI_OUT || EPI == EPI_FF2) {
            int orow = (EPI == EPI_OUT && trans) ? ((grow % NSEQ) * NSEQ + grow / NSEQ) : grow;
            const float* rp = e_resid + (size_t)orow * DIM + gc0;
            float* op = e_outf + (size_t)orow * DIM + gc0;
            #pragma unroll
            for (int q = 0; q < 4; ++q) {
                float4 r4 = *(const float4*)(rp + q * 4);
                float4 o4;
                o4.x = v[q*4+0] + e_bias[gc0 + q*4 + 0] + r4.x;
                o4.y = v[q*4+1] + e_bias[gc0 + q*4 + 1] + r4.y;
                o4.z = v[q*4+2] + e_bias[gc0 + q*4 + 2] + r4.z;
                o4.w = v[q*4+3] + e_bias[gc0 + q*4 + 3] + r4.w;
                *(float4*)(op + q * 4) = o4;
            }
        } else { // EPI_GEGLU
            short o8[8];
            #pragma unroll
            for (int t = 0; t < 8; ++t) {
                float a  = v[2*t]     + e_bias[n0 + gc0 + 2*t];
                float gg = v[2*t + 1] + e_bias[n0 + gc0 + 2*t + 1];
                float y  = 1.5957691216f * (gg + 0.044715f * gg * gg * gg);
                float ge = gg / (1.0f + __expf(-y));   // tanh-form GELU
                o8[t] = f2bs(a * ge);
            }
            *(uint4*)(e_outb + (size_t)grow * 512 + ((n0 + gc0) >> 1)) = *(uint4*)o8;
        }
    }
}

// ---------------- MFMA flash attention: block=(h,r), 4 waves x 48 q-rows ---------------
__global__ __launch_bounds__(256)
void attn_mfma_kernel(const bf16* __restrict__ Qh, const bf16* __restrict__ Kh,
                      const bf16* __restrict__ Vh, const float* __restrict__ BIAS,
                      const bf16* __restrict__ G, bf16* __restrict__ TMP)
{
    __shared__ unsigned short vtp[32][200];   // V^T permuted, row stride 400B (16B mult)
    int h = blockIdx.x / NSEQ;
    int r = blockIdx.x % NSEQ;
    int t = threadIdx.x;
    int l = t & 63;
    int w = t >> 6;

    // ---- stage V^T permuted: vtp[e][sup*32 + f(k')] = V[k][e] ----
    const bf16* vbase = Vh + ((size_t)h * MROWS + (size_t)r * NSEQ) * DHEAD;
    #pragma unroll
    for (int i = 0; i < 6; ++i) {
        int q4 = t + i * 256;                 // 1536 quads
        int k = q4 >> 3, e0 = (q4 & 7) * 4;
        uint2 v = *(const uint2*)(vbase + (size_t)k * DHEAD + e0);
        int kk = k & 31, sup = k >> 5;
        int col = sup * 32 + ((kk & 15) >> 2) * 8 + (kk & 3) + ((kk >> 4) << 2);
        const unsigned short* vs = (const unsigned short*)&v;
        #pragma unroll
        for (int j = 0; j < 4; ++j) vtp[e0 + j][col] = vs[j];
    }
    __syncthreads();

    int fr = l & 15, g = l >> 4;
    int q0 = w * 48;
    const bf16*  qbase = Qh + ((size_t)h * MROWS + (size_t)r * NSEQ) * DHEAD;
    const bf16*  kbase = Kh + ((size_t)h * MROWS + (size_t)r * NSEQ) * DHEAD;
    const float* bbase = BIAS + (size_t)h * MROWS;

    bf16x8 qf[3];
    #pragma unroll
    for (int i = 0; i < 3; ++i)
        qf[i] = *(const bf16x8*)(qbase + (size_t)(q0 + i * 16 + fr) * DHEAD + g * 8);

    f32x4 ot[3][2] = {};
    float m_[3] = {-1e30f, -1e30f, -1e30f};
    float s_[3] = {};

    for (int sup = 0; sup < 6; ++sup) {
        bf16x8 kf0 = *(const bf16x8*)(kbase + (size_t)(sup * 32 + fr) * DHEAD + g * 8);
        bf16x8 kf1 = *(const bf16x8*)(kbase + (size_t)(sup * 32 + 16 + fr) * DHEAD + g * 8);
        bf16x8 pb[3];
        #pragma unroll
        for (int qt = 0; qt < 3; ++qt) {
            f32x4 z = {};
            f32x4 s0 = __builtin_amdgcn_mfma_f32_16x16x32_bf16(kf0, qf[qt], z, 0, 0, 0);
            f32x4 s1 = __builtin_amdgcn_mfma_f32_16x16x32_bf16(kf1, qf[qt], z, 0, 0, 0);
            const float* bp = bbase + (size_t)(q0 + qt * 16 + fr) * NSEQ + sup * 32 + g * 4;
            float4 b0 = *(const float4*)bp;
            float4 b1 = *(const float4*)(bp + 16);
            s0[0] += b0.x; s0[1] += b0.y; s0[2] += b0.z; s0[3] += b0.w;
            s1[0] += b1.x; s1[1] += b1.y; s1[2] += b1.z; s1[3] += b1.w;
            float tmax = fmaxf(fmaxf(fmaxf(s0[0], s0[1]), fmaxf(s0[2], s0[3])),
                               fmaxf(fmaxf(s1[0], s1[1]), fmaxf(s1[2], s1[3])));
            tmax = fmaxf(tmax, __shfl_xor(tmax, 16));
            tmax = fmaxf(tmax, __shfl_xor(tmax, 32));
            if (__any(tmax > m_[qt] + 8.0f)) {       // defer-max (T13)
                float mn = fmaxf(m_[qt], tmax);
                float c = __expf(m_[qt] - mn);
                s_[qt] *= c; ot[qt][0] *= c; ot[qt][1] *= c;
                m_[qt] = mn;
            }
            float p[8];
            #pragma unroll
            for (int j = 0; j < 4; ++j) p[j]     = __expf(s0[j] - m_[qt]);
            #pragma unroll
            for (int j = 0; j < 4; ++j) p[4 + j] = __expf(s1[j] - m_[qt]);
            s_[qt] += ((p[0] + p[1]) + (p[2] + p[3])) + ((p[4] + p[5]) + (p[6] + p[7]));
            bf16x8 pk;
            #pragma unroll
            for (int j = 0; j < 8; ++j) pk[j] = f2bs(p[j]);
            pb[qt] = pk;
        }
        #pragma unroll
        for (int et = 0; et < 2; ++et) {
            bf16x8 vf = *(const bf16x8*)(&vtp[et * 16 + fr][sup * 32 + g * 8]);
            #pragma unroll
            for (int qt = 0; qt < 3; ++qt)
                ot[qt][et] = __builtin_amdgcn_mfma_f32_16x16x32_bf16(vf, pb[qt], ot[qt][et], 0, 0, 0);
        }
    }

    // ---- epilogue: O = O^T/s * gate, bf16 store ----
    #pragma unroll
    for (int qt = 0; qt < 3; ++qt) {
        float sq = s_[qt];
        sq += __shfl_xor(sq, 16);
        sq += __shfl_xor(sq, 32);
        float inv = 1.0f / sq;
        int q = q0 + qt * 16 + fr;
        size_t row = (size_t)r * NSEQ + q;
        #pragma unroll
        for (int et = 0; et < 2; ++et) {
            int e0 = h * DHEAD + et * 16 + g * 4;
            const bf16* gp = G + row * DIM + e0;
            u32 g01 = *(const u32*)gp;
            u32 g23 = *(const u32*)(gp + 2);
            float gx0 = __uint_as_float((g01 & 0xffffu) << 16);
            float gx1 = __uint_as_float(g01 & 0xffff0000u);
            float gx2 = __uint_as_float((g23 & 0xffffu) << 16);
            float gx3 = __uint_as_float(g23 & 0xffff0000u);
            short o4[4];
            o4[0] = f2bs(ot[qt][et][0] * inv * gx0);
            o4[1] = f2bs(ot[qt][et][1] * inv * gx1);
            o4[2] = f2bs(ot[qt][et][2] * inv * gx2);
            o4[3] = f2bs(ot[qt][et][3] * inv * gx3);
            *(uint2*)(TMP + row * DIM + e0) = *(uint2*)o4;
        }
    }
}

extern "C" void kernel_launch(void* const* d_in, const int* in_sizes, int n_in,
                              void* d_out, int out_size, void* d_ws, size_t ws_size,
                              hipStream_t stream) {
    const float* x     = (const float*)d_in[0];
    const float* lng_o = (const float*)d_in[1];
    const float* lnb_o = (const float*)d_in[2];
    const float* wq_o  = (const float*)d_in[3];
    const float* wkv_o = (const float*)d_in[4];
    const float* wo_o  = (const float*)d_in[5];
    const float* bo_o  = (const float*)d_in[6];
    const float* wg_o  = (const float*)d_in[7];
    const float* bg_o  = (const float*)d_in[8];
    const float* wb_o  = (const float*)d_in[9];
    const float* lng_i = (const float*)d_in[10];
    const float* lnb_i = (const float*)d_in[11];
    const float* wq_i  = (const float*)d_in[12];
    const float* wkv_i = (const float*)d_in[13];
    const float* wo_i  = (const float*)d_in[14];
    const float* bo_i  = (const float*)d_in[15];
    const float* wg_i  = (const float*)d_in[16];
    const float* bg_i  = (const float*)d_in[17];
    const float* wb_i  = (const float*)d_in[18];
    const float* lng_f = (const float*)d_in[19];
    const float* lnb_f = (const float*)d_in[20];
    const float* w1    = (const float*)d_in[21];
    const float* b1    = (const float*)d_in[22];
    const float* w2    = (const float*)d_in[23];
    const float* b2    = (const float*)d_in[24];

    const size_t T = (size_t)MROWS * DIM;
    char* base = (char*)d_ws;
    bf16*  XA    = (bf16*)base;  base += T * 2;            // bf16 LN output
    float* X     = (float*)base; base += T * 4;            // f32 running residual
    bf16*  QKVb  = (bf16*)base;  base += 3 * T * 2;        // Q,K,V bf16 [3][4][MROWS][32]
    bf16*  Gb    = (bf16*)base;  base += T * 2;            // gate bf16 [MROWS][128]
    float* BIASb = (float*)base; base += (size_t)NH * MROWS * 4;
    bf16*  TMP   = (bf16*)base;  base += T * 2;            // o*gates bf16
    bf16*  WQKVG_O = (bf16*)base; base += 512 * 128 * 2;
    bf16*  WQKVG_I = (bf16*)base; base += 512 * 128 * 2;
    bf16*  WOT_O   = (bf16*)base; base += 128 * 128 * 2;
    bf16*  WOT_I   = (bf16*)base; base += 128 * 128 * 2;
    bf16*  W1PT    = (bf16*)base; base += 1024 * 128 * 2;
    bf16*  W2T     = (bf16*)base; base += 128 * 512 * 2;
    float* B1P     = (float*)base; base += 1024 * 4;
    bf16*  H2      = (bf16*)QKVb;  // overlay: QKVb+Gb free during FFN (37.7MB = H2 size)
    bf16*  Qhp = QKVb;
    bf16*  Khp = QKVb + T;
    bf16*  Vhp = QKVb + 2 * T;

    convert_weights<<<1412, 256, 0, stream>>>(wq_o, wkv_o, wg_o, wq_i, wkv_i, wg_i,
                                              wo_o, wo_i, w1, b1, w2,
                                              WQKVG_O, WQKVG_I, WOT_O, WOT_I,
                                              W1PT, W2T, B1P);

    dim3 gQKVG(MROWS / 128, 4), gN128(MROWS / 128, 1), gW1(MROWS / 128, 8);
    dim3 gFF2(MROWS / 64, 1);

    // ---- stage 1: row attention, x -> X ----
    ln_bias_kernel<<<MROWS / 4, 256, 0, stream>>>(x, lng_o, lnb_o, wb_o, XA, BIASb, 0);
    mfma_gemm<EPI_QKVG, 128, 128><<<gQKVG, 256, 0, stream>>>(XA, WQKVG_O, bg_o, nullptr, nullptr, QKVb, Gb, 0);
    attn_mfma_kernel<<<NSEQ * NH, 256, 0, stream>>>(Qhp, Khp, Vhp, BIASb, Gb, TMP);
    mfma_gemm<EPI_OUT, 128, 128><<<gN128, 256, 0, stream>>>(TMP, WOT_O, bo_o, x, X, nullptr, nullptr, 0);

    // ---- stage 2: col attention, X -> X (transposed store is a bijection) ----
    ln_bias_kernel<<<MROWS / 4, 256, 0, stream>>>(X, lng_i, lnb_i, wb_i, XA, BIASb, 1);
    mfma_gemm<EPI_QKVG, 128, 128><<<gQKVG, 256, 0, stream>>>(XA, WQKVG_I, bg_i, nullptr, nullptr, QKVb, Gb, 0);
    attn_mfma_kernel<<<NSEQ * NH, 256, 0, stream>>>(Qhp, Khp, Vhp, BIASb, Gb, TMP);
    mfma_gemm<EPI_OUT, 128, 128><<<gN128, 256, 0, stream>>>(TMP, WOT_I, bo_i, X, X, nullptr, nullptr, 1);

    // ---- FFN: xn = LN(X); H2 = geglu(xn@w1p+b1p); out = H2@w2 + b2 + X ----
    ln_bias_kernel<<<MROWS / 4, 256, 0, stream>>>(X, lng_f, lnb_f, nullptr, XA, nullptr, 0);
    mfma_gemm<EPI_GEGLU, 128, 128><<<gW1, 256, 0, stream>>>(XA, W1PT, B1P, nullptr, nullptr, H2, nullptr, 0);
    mfma_gemm<EPI_FF2, 64, 512><<<gFF2, 256, 0, stream>>>(H2, W2T, b2, X, (float*)d_out, nullptr, nullptr, 0);
}

// Round 5
// 231.174 us; speedup vs baseline: 4.4703x; 1.0425x over previous
//
#include <hip/hip_runtime.h>
#include <hip/hip_bf16.h>
#include <math.h>

constexpr int NSEQ = 192;
constexpr int DIM  = 128;
constexpr int NH   = 4;
constexpr int DHEAD = 32;
constexpr int MROWS = NSEQ * NSEQ; // 36864

typedef __hip_bfloat16 bf16;
typedef __attribute__((ext_vector_type(8))) short bf16x8;
typedef __attribute__((ext_vector_type(4))) float f32x4;
typedef unsigned int u32;

__device__ __forceinline__ void gload16(const void* g, void* l) {
    __builtin_amdgcn_global_load_lds(
        (const __attribute__((address_space(1))) u32*)g,
        (__attribute__((address_space(3))) u32*)l, 16, 0, 0);
}

__device__ __forceinline__ short f2bs(float f) {
    __hip_bfloat16 h = __float2bfloat16(f);
    return *(short*)&h;
}

// ---------------- Weight prep: f32 -> bf16, transpose to B^T [N][K], fuse/fold ---------
__global__ __launch_bounds__(256)
void convert_weights(const float* __restrict__ wq_o, const float* __restrict__ wkv_o,
                     const float* __restrict__ wg_o,
                     const float* __restrict__ wq_i, const float* __restrict__ wkv_i,
                     const float* __restrict__ wg_i,
                     const float* __restrict__ wo_o, const float* __restrict__ wo_i,
                     const float* __restrict__ w1, const float* __restrict__ b1,
                     const float* __restrict__ w2,
                     bf16* __restrict__ WQKVG_O, bf16* __restrict__ WQKVG_I,
                     bf16* __restrict__ WOT_O, bf16* __restrict__ WOT_I,
                     bf16* __restrict__ W1PT, bf16* __restrict__ W2T,
                     float* __restrict__ B1P)
{
    int idx = blockIdx.x * 256 + threadIdx.x;
    const float scale = 0.17677669529663689f; // 32^-0.5 folded into wq
    if (idx < 131072) {                       // WQKVG_{o,i}: [512][128], rows q|k|v|g
        int s = idx >> 16, i = idx & 65535;
        int r = i >> 7, d = i & 127;
        const float* wq  = s ? wq_i  : wq_o;
        const float* wkv = s ? wkv_i : wkv_o;
        const float* wg  = s ? wg_i  : wg_o;
        float v;
        if (r < 128)      v = wq[d * 128 + r] * scale;
        else if (r < 384) v = wkv[d * 256 + (r - 128)];   // k: cols 0..127, v: 128..255
        else              v = wg[d * 128 + (r - 384)];
        (s ? WQKVG_I : WQKVG_O)[i] = __float2bfloat16(v);
    } else if (idx < 163840) {                // WOT_{o,i}: [128][128] = wo^T
        int i = idx - 131072; int s = i >> 14; i &= 16383;
        int r = i >> 7, d = i & 127;
        (s ? WOT_I : WOT_O)[i] = __float2bfloat16((s ? wo_i : wo_o)[d * 128 + r]);
    } else if (idx < 294912) {                // W1PT: [1024][128], rows 2j=a_j, 2j+1=g_j
        int i = idx - 163840;
        int r = i >> 7, d = i & 127;
        int col = (r & 1) ? 512 + (r >> 1) : (r >> 1);
        W1PT[i] = __float2bfloat16(w1[d * 1024 + col]);
    } else if (idx < 360448) {                // W2T: [128][512] = w2^T
        int i = idx - 294912;
        int n = i >> 9, k = i & 511;
        W2T[i] = __float2bfloat16(w2[k * 128 + n]);
    } else if (idx < 361472) {                // B1P: paired bias
        int r = idx - 360448;
        B1P[r] = b1[(r & 1) ? 512 + (r >> 1) : (r >> 1)];
    }
}

// ---------------- LayerNorm (+ bias-projection), bf16 out (stage-1 input only) --------
__global__ __launch_bounds__(256)
void ln_bias_kernel(const float* __restrict__ x, const float* __restrict__ g,
                    const float* __restrict__ b, const float* __restrict__ wb,
                    bf16* __restrict__ xa, float* __restrict__ bias)
{
    int wid  = threadIdx.x >> 6;
    int lane = threadIdx.x & 63;
    int row  = blockIdx.x * 4 + wid;
    const float* xr = x + (size_t)row * DIM;
    float x0 = xr[lane], x1 = xr[lane + 64];
    float s = x0 + x1, sq = x0 * x0 + x1 * x1;
    #pragma unroll
    for (int off = 32; off > 0; off >>= 1) {
        s  += __shfl_down(s, off);
        sq += __shfl_down(sq, off);
    }
    s = __shfl(s, 0); sq = __shfl(sq, 0);
    float mu  = s * (1.0f / 128.0f);
    float var = sq * (1.0f / 128.0f) - mu * mu;
    float rs  = rsqrtf(var + 1e-5f);
    float y0 = (x0 - mu) * rs * g[lane]      + b[lane];
    float y1 = (x1 - mu) * rs * g[lane + 64] + b[lane + 64];
    bf16* yr = xa + (size_t)row * DIM;
    yr[lane]      = __float2bfloat16(y0);
    yr[lane + 64] = __float2bfloat16(y1);
    #pragma unroll
    for (int h = 0; h < NH; ++h) {
        float bh = x0 * wb[lane * NH + h] + x1 * wb[(lane + 64) * NH + h];
        #pragma unroll
        for (int off = 32; off > 0; off >>= 1) bh += __shfl_down(bh, off);
        if (lane == 0) bias[(size_t)h * MROWS + row] = bh;
    }
}

// ---------------- bf16 MFMA GEMM, BK=64, 32KB LDS, fused epilogues ---------------------
// BM x 128 tile, 4 waves (2x2), 16x16x32 MFMA. Stage: global_load_lds 16B, source atom
// pre-swizzled (atom = lane&7 ^ lane>>3); reads XOR (row&7)<<4 -> conflict-free.
// Epilogue: two half-tile rounds through 32KB f32 LDS with bijective atom perm
// pi(a) = ((ch+q)&7)|(q<<3)  (conflict-free write AND read phases).
// EPI_OUT additionally fuses the next LayerNorm (+ optional wb bias projection).
enum { EPI_QKVG = 0, EPI_OUT = 1, EPI_GEGLU = 2, EPI_FF2 = 3 };

template<int EPI, int BM, int K>
__global__ __launch_bounds__(256, 4)
void mfma_gemm(const bf16* __restrict__ A, const bf16* __restrict__ BT,
               const float* __restrict__ e_bias,   // bg | bo | b1p | b2
               const float* __restrict__ e_resid,  // -  | xin | -   | X
               float* __restrict__ e_outf,         // -  | X   | -   | out
               bf16* __restrict__ e_outb,          // QKV| -   | H2  | -
               bf16* __restrict__ e_outb2,         // Gb | -   | -   | -
               const float* __restrict__ lng,      // next-LN gamma (OUT)
               const float* __restrict__ lnb,      // next-LN beta  (OUT)
               const float* __restrict__ wbp,      // next-stage wb [128][4] (OUT1)
               float* __restrict__ biasb,          // next-stage bias out (OUT1)
               bf16* __restrict__ xa,              // next-LN output (OUT)
               int trans)
{
    constexpr int MREP  = BM / 32;
    constexpr int AB    = BM * 128;
    constexpr int STAGE = AB + 16384;
    constexpr int EPIB  = (BM / 2) * 512;
    constexpr int LDSB  = STAGE > EPIB ? STAGE : EPIB;
    __shared__ char sm[LDSB];
    char* asb = sm;
    char* bsb = sm + AB;
    float* eb = (float*)sm;

    int tid = threadIdx.x;
    int l = tid & 63, w = tid >> 6;
    int wr = w >> 1, wc = w & 1;
    int m0 = blockIdx.x * BM, n0 = blockIdx.y * 128;
    int fr = l & 15, g = l >> 4;
    int lr8 = l >> 3;
    int satom = (l & 7) ^ lr8;

    f32x4 acc[MREP][4] = {};

    for (int k0 = 0; k0 < K; k0 += 64) {
        #pragma unroll
        for (int i = 0; i < BM / 32; ++i)
            gload16(A + (size_t)(m0 + i * 32 + w * 8 + lr8) * K + k0 + satom * 8,
                    asb + i * 4096 + w * 1024);
        #pragma unroll
        for (int i = 0; i < 4; ++i)
            gload16(BT + (size_t)(n0 + i * 32 + w * 8 + lr8) * K + k0 + satom * 8,
                    bsb + i * 4096 + w * 1024);
        __syncthreads();
        #pragma unroll
        for (int kk = 0; kk < 2; ++kk) {
            bf16x8 af[MREP], bfr[4];
            #pragma unroll
            for (int mi = 0; mi < MREP; ++mi) {
                int r = wr * (BM / 2) + mi * 16 + fr;
                af[mi] = *(const bf16x8*)(asb + r * 128 + ((kk * 64 + g * 16) ^ ((r & 7) << 4)));
            }
            #pragma unroll
            for (int ni = 0; ni < 4; ++ni) {
                int r = wc * 64 + ni * 16 + fr;
                bfr[ni] = *(const bf16x8*)(bsb + r * 128 + ((kk * 64 + g * 16) ^ ((r & 7) << 4)));
            }
            #pragma unroll
            for (int mi = 0; mi < MREP; ++mi)
                #pragma unroll
                for (int ni = 0; ni < 4; ++ni)
                    acc[mi][ni] = __builtin_amdgcn_mfma_f32_16x16x32_bf16(
                        af[mi], bfr[ni], acc[mi][ni], 0, 0, 0);
        }
        __syncthreads();
    }

    // ---- epilogue: two half-tile rounds through LDS ----
    #pragma unroll
    for (int rr = 0; rr < 2; ++rr) {
        if (wr == rr) {
            #pragma unroll
            for (int mi = 0; mi < MREP; ++mi)
                #pragma unroll
                for (int ni = 0; ni < 4; ++ni)
                    #pragma unroll
                    for (int j = 0; j < 4; ++j) {
                        int rl = mi * 16 + g * 4 + j;
                        int cl = wc * 64 + ni * 16 + fr;
                        int a  = cl >> 2;
                        int pa = (((a >> 2) + (a & 3)) & 7) | ((a & 3) << 3);
                        eb[rl * 128 + pa * 4 + (cl & 3)] = acc[mi][ni][j];
                    }
        }
        __syncthreads();
        #pragma unroll
        for (int p = 0; p < BM / 64; ++p) {
            int c = tid + p * 256;
            int row_l = c >> 3, ch = c & 7;
            int grow = m0 + rr * (BM / 2) + row_l;
            int gc0 = ch * 16;
            float v[16];
            #pragma unroll
            for (int q = 0; q < 4; ++q) {
                int pa = ((ch + q) & 7) + q * 8;
                f32x4 t4 = *(const f32x4*)&eb[row_l * 128 + pa * 4];
                v[q * 4 + 0] = t4[0]; v[q * 4 + 1] = t4[1];
                v[q * 4 + 2] = t4[2]; v[q * 4 + 3] = t4[3];
            }
            if (EPI == EPI_QKVG) {
                int seg = blockIdx.y;
                short o16[16];
                if (seg < 3) {
                    #pragma unroll
                    for (int i = 0; i < 16; ++i) o16[i] = f2bs(v[i]);
                    int h = ch >> 1, e0 = (ch & 1) * 16;
                    bf16* dst = e_outb + ((size_t)(seg * NH + h) * MROWS + grow) * DHEAD + e0;
                    *(uint4*)dst = *(uint4*)o16;
                    *(uint4*)(dst + 8) = *(uint4*)(o16 + 8);
                } else {
                    #pragma unroll
                    for (int i = 0; i < 16; ++i)
                        o16[i] = f2bs(1.0f / (1.0f + __expf(-(v[i] + e_bias[gc0 + i]))));
                    bf16* dst = e_outb2 + (size_t)grow * DIM + gc0;
                    *(uint4*)dst = *(uint4*)o16;
                    *(uint4*)(dst + 8) = *(uint4*)(o16 + 8);
                }
            } else if (EPI == EPI_OUT) {
                int orow  = trans ? ((grow % NSEQ) * NSEQ + grow / NSEQ) : grow;
                int xarow = (grow % NSEQ) * NSEQ + grow / NSEQ;  // transpose(grow) both stages
                const float* rp = e_resid + (size_t)orow * DIM + gc0;
                float* op = e_outf + (size_t)orow * DIM + gc0;
                #pragma unroll
                for (int q = 0; q < 4; ++q) {
                    float4 r4 = *(const float4*)(rp + q * 4);
                    v[q*4+0] += e_bias[gc0 + q*4 + 0] + r4.x;
                    v[q*4+1] += e_bias[gc0 + q*4 + 1] + r4.y;
                    v[q*4+2] += e_bias[gc0 + q*4 + 2] + r4.z;
                    v[q*4+3] += e_bias[gc0 + q*4 + 3] + r4.w;
                    *(float4*)(op + q * 4) = make_float4(v[q*4+0], v[q*4+1], v[q*4+2], v[q*4+3]);
                }
                // fused next-LN over the 128-wide row (8 threads per row)
                float s1 = 0.f, s2 = 0.f;
                #pragma unroll
                for (int i = 0; i < 16; ++i) { s1 += v[i]; s2 += v[i] * v[i]; }
                #pragma unroll
                for (int off = 1; off < 8; off <<= 1) {
                    s1 += __shfl_xor(s1, off);
                    s2 += __shfl_xor(s2, off);
                }
                float mu  = s1 * (1.0f / 128.0f);
                float var = s2 * (1.0f / 128.0f) - mu * mu;
                float rs  = rsqrtf(var + 1e-5f);
                short o16[16];
                #pragma unroll
                for (int i = 0; i < 16; ++i)
                    o16[i] = f2bs((v[i] - mu) * rs * lng[gc0 + i] + lnb[gc0 + i]);
                bf16* xd = xa + (size_t)xarow * DIM + gc0;
                *(uint4*)xd = *(uint4*)o16;
                *(uint4*)(xd + 8) = *(uint4*)(o16 + 8);
                // fused next-stage bias projection (stage1->stage2 only)
                if (wbp) {
                    float bh[NH] = {};
                    #pragma unroll
                    for (int i = 0; i < 16; ++i) {
                        float vv = v[i];
                        #pragma unroll
                        for (int h = 0; h < NH; ++h)
                            bh[h] = fmaf(vv, wbp[(gc0 + i) * NH + h], bh[h]);
                    }
                    #pragma unroll
                    for (int off = 1; off < 8; off <<= 1)
                        #pragma unroll
                        for (int h = 0; h < NH; ++h) bh[h] += __shfl_xor(bh[h], off);
                    if (ch == 0)
                        #pragma unroll
                        for (int h = 0; h < NH; ++h)
                            biasb[(size_t)h * MROWS + grow] = bh[h];
                }
            } else if (EPI == EPI_FF2) {
                const float* rp = e_resid + (size_t)grow * DIM + gc0;
                float* op = e_outf + (size_t)grow * DIM + gc0;
                #pragma unroll
                for (int q = 0; q < 4; ++q) {
                    float4 r4 = *(const float4*)(rp + q * 4);
                    float4 o4;
                    o4.x = v[q*4+0] + e_bias[gc0 + q*4 + 0] + r4.x;
                    o4.y = v[q*4+1] + e_bias[gc0 + q*4 + 1] + r4.y;
                    o4.z = v[q*4+2] + e_bias[gc0 + q*4 + 2] + r4.z;
                    o4.w = v[q*4+3] + e_bias[gc0 + q*4 + 3] + r4.w;
                    *(float4*)(op + q * 4) = o4;
                }
            } else { // EPI_GEGLU
                short o8[8];
                #pragma unroll
                for (int t = 0; t < 8; ++t) {
                    float a  = v[2*t]     + e_bias[n0 + gc0 + 2*t];
                    float gg = v[2*t + 1] + e_bias[n0 + gc0 + 2*t + 1];
                    float y  = 1.5957691216f * (gg + 0.044715f * gg * gg * gg);
                    float ge = gg / (1.0f + __expf(-y));   // tanh-form GELU
                    o8[t] = f2bs(a * ge);
                }
                *(uint4*)(e_outb + (size_t)grow * 512 + ((n0 + gc0) >> 1)) = *(uint4*)o8;
            }
        }
        __syncthreads();
    }
}

// ---------------- MFMA flash attention: block=(h,r), 4 waves x 48 q-rows ---------------
__global__ __launch_bounds__(256)
void attn_mfma_kernel(const bf16* __restrict__ Qh, const bf16* __restrict__ Kh,
                      const bf16* __restrict__ Vh, const float* __restrict__ BIAS,
                      const bf16* __restrict__ G, bf16* __restrict__ TMP)
{
    __shared__ unsigned short vtp[32][200];   // V^T permuted, row stride 400B (16B mult)
    int h = blockIdx.x / NSEQ;
    int r = blockIdx.x % NSEQ;
    int t = threadIdx.x;
    int l = t & 63;
    int w = t >> 6;

    // ---- stage V^T permuted: vtp[e][sup*32 + f(k')] = V[k][e] ----
    const bf16* vbase = Vh + ((size_t)h * MROWS + (size_t)r * NSEQ) * DHEAD;
    #pragma unroll
    for (int i = 0; i < 6; ++i) {
        int q4 = t + i * 256;                 // 1536 quads
        int k = q4 >> 3, e0 = (q4 & 7) * 4;
        uint2 v = *(const uint2*)(vbase + (size_t)k * DHEAD + e0);
        int kk = k & 31, sup = k >> 5;
        int col = sup * 32 + ((kk & 15) >> 2) * 8 + (kk & 3) + ((kk >> 4) << 2);
        const unsigned short* vs = (const unsigned short*)&v;
        #pragma unroll
        for (int j = 0; j < 4; ++j) vtp[e0 + j][col] = vs[j];
    }
    __syncthreads();

    int fr = l & 15, g = l >> 4;
    int q0 = w * 48;
    const bf16*  qbase = Qh + ((size_t)h * MROWS + (size_t)r * NSEQ) * DHEAD;
    const bf16*  kbase = Kh + ((size_t)h * MROWS + (size_t)r * NSEQ) * DHEAD;
    const float* bbase = BIAS + (size_t)h * MROWS;

    bf16x8 qf[3];
    #pragma unroll
    for (int i = 0; i < 3; ++i)
        qf[i] = *(const bf16x8*)(qbase + (size_t)(q0 + i * 16 + fr) * DHEAD + g * 8);

    f32x4 ot[3][2] = {};
    float m_[3] = {-1e30f, -1e30f, -1e30f};
    float s_[3] = {};

    for (int sup = 0; sup < 6; ++sup) {
        bf16x8 kf0 = *(const bf16x8*)(kbase + (size_t)(sup * 32 + fr) * DHEAD + g * 8);
        bf16x8 kf1 = *(const bf16x8*)(kbase + (size_t)(sup * 32 + 16 + fr) * DHEAD + g * 8);
        bf16x8 pb[3];
        #pragma unroll
        for (int qt = 0; qt < 3; ++qt) {
            f32x4 z = {};
            f32x4 s0 = __builtin_amdgcn_mfma_f32_16x16x32_bf16(kf0, qf[qt], z, 0, 0, 0);
            f32x4 s1 = __builtin_amdgcn_mfma_f32_16x16x32_bf16(kf1, qf[qt], z, 0, 0, 0);
            const float* bp = bbase + (size_t)(q0 + qt * 16 + fr) * NSEQ + sup * 32 + g * 4;
            float4 b0 = *(const float4*)bp;
            float4 b1 = *(const float4*)(bp + 16);
            s0[0] += b0.x; s0[1] += b0.y; s0[2] += b0.z; s0[3] += b0.w;
            s1[0] += b1.x; s1[1] += b1.y; s1[2] += b1.z; s1[3] += b1.w;
            float tmax = fmaxf(fmaxf(fmaxf(s0[0], s0[1]), fmaxf(s0[2], s0[3])),
                               fmaxf(fmaxf(s1[0], s1[1]), fmaxf(s1[2], s1[3])));
            tmax = fmaxf(tmax, __shfl_xor(tmax, 16));
            tmax = fmaxf(tmax, __shfl_xor(tmax, 32));
            if (__any(tmax > m_[qt] + 8.0f)) {       // defer-max (T13)
                float mn = fmaxf(m_[qt], tmax);
                float c = __expf(m_[qt] - mn);
                s_[qt] *= c; ot[qt][0] *= c; ot[qt][1] *= c;
                m_[qt] = mn;
            }
            float p[8];
            #pragma unroll
            for (int j = 0; j < 4; ++j) p[j]     = __expf(s0[j] - m_[qt]);
            #pragma unroll
            for (int j = 0; j < 4; ++j) p[4 + j] = __expf(s1[j] - m_[qt]);
            s_[qt] += ((p[0] + p[1]) + (p[2] + p[3])) + ((p[4] + p[5]) + (p[6] + p[7]));
            bf16x8 pk;
            #pragma unroll
            for (int j = 0; j < 8; ++j) pk[j] = f2bs(p[j]);
            pb[qt] = pk;
        }
        #pragma unroll
        for (int et = 0; et < 2; ++et) {
            bf16x8 vf = *(const bf16x8*)(&vtp[et * 16 + fr][sup * 32 + g * 8]);
            #pragma unroll
            for (int qt = 0; qt < 3; ++qt)
                ot[qt][et] = __builtin_amdgcn_mfma_f32_16x16x32_bf16(vf, pb[qt], ot[qt][et], 0, 0, 0);
        }
    }

    // ---- epilogue: O = O^T/s * gate, bf16 store ----
    #pragma unroll
    for (int qt = 0; qt < 3; ++qt) {
        float sq = s_[qt];
        sq += __shfl_xor(sq, 16);
        sq += __shfl_xor(sq, 32);
        float inv = 1.0f / sq;
        int q = q0 + qt * 16 + fr;
        size_t row = (size_t)r * NSEQ + q;
        #pragma unroll
        for (int et = 0; et < 2; ++et) {
            int e0 = h * DHEAD + et * 16 + g * 4;
            const bf16* gp = G + row * DIM + e0;
            u32 g01 = *(const u32*)gp;
            u32 g23 = *(const u32*)(gp + 2);
            float gx0 = __uint_as_float((g01 & 0xffffu) << 16);
            float gx1 = __uint_as_float(g01 & 0xffff0000u);
            float gx2 = __uint_as_float((g23 & 0xffffu) << 16);
            float gx3 = __uint_as_float(g23 & 0xffff0000u);
            short o4[4];
            o4[0] = f2bs(ot[qt][et][0] * inv * gx0);
            o4[1] = f2bs(ot[qt][et][1] * inv * gx1);
            o4[2] = f2bs(ot[qt][et][2] * inv * gx2);
            o4[3] = f2bs(ot[qt][et][3] * inv * gx3);
            *(uint2*)(TMP + row * DIM + e0) = *(uint2*)o4;
        }
    }
}

extern "C" void kernel_launch(void* const* d_in, const int* in_sizes, int n_in,
                              void* d_out, int out_size, void* d_ws, size_t ws_size,
                              hipStream_t stream) {
    const float* x     = (const float*)d_in[0];
    const float* lng_o = (const float*)d_in[1];
    const float* lnb_o = (const float*)d_in[2];
    const float* wq_o  = (const float*)d_in[3];
    const float* wkv_o = (const float*)d_in[4];
    const float* wo_o  = (const float*)d_in[5];
    const float* bo_o  = (const float*)d_in[6];
    const float* wg_o  = (const float*)d_in[7];
    const float* bg_o  = (const float*)d_in[8];
    const float* wb_o  = (const float*)d_in[9];
    const float* lng_i = (const float*)d_in[10];
    const float* lnb_i = (const float*)d_in[11];
    const float* wq_i  = (const float*)d_in[12];
    const float* wkv_i = (const float*)d_in[13];
    const float* wo_i  = (const float*)d_in[14];
    const float* bo_i  = (const float*)d_in[15];
    const float* wg_i  = (const float*)d_in[16];
    const float* bg_i  = (const float*)d_in[17];
    const float* wb_i  = (const float*)d_in[18];
    const float* lng_f = (const float*)d_in[19];
    const float* lnb_f = (const float*)d_in[20];
    const float* w1    = (const float*)d_in[21];
    const float* b1    = (const float*)d_in[22];
    const float* w2    = (const float*)d_in[23];
    const float* b2    = (const float*)d_in[24];

    const size_t T = (size_t)MROWS * DIM;
    char* base = (char*)d_ws;
    bf16*  XA    = (bf16*)base;  base += T * 2;            // bf16 LN output
    float* X     = (float*)base; base += T * 4;            // f32 running residual
    bf16*  QKVb  = (bf16*)base;  base += 3 * T * 2;        // Q,K,V bf16 [3][4][MROWS][32]
    bf16*  Gb    = (bf16*)base;  base += T * 2;            // gate bf16 [MROWS][128]
    float* BIASb = (float*)base; base += (size_t)NH * MROWS * 4;
    bf16*  TMP   = (bf16*)base;  base += T * 2;            // o*gates bf16
    bf16*  WQKVG_O = (bf16*)base; base += 512 * 128 * 2;
    bf16*  WQKVG_I = (bf16*)base; base += 512 * 128 * 2;
    bf16*  WOT_O   = (bf16*)base; base += 128 * 128 * 2;
    bf16*  WOT_I   = (bf16*)base; base += 128 * 128 * 2;
    bf16*  W1PT    = (bf16*)base; base += 1024 * 128 * 2;
    bf16*  W2T     = (bf16*)base; base += 128 * 512 * 2;
    float* B1P     = (float*)base; base += 1024 * 4;
    bf16*  H2      = (bf16*)QKVb;  // overlay: QKVb+Gb free during FFN (37.7MB = H2 size)
    bf16*  Qhp = QKVb;
    bf16*  Khp = QKVb + T;
    bf16*  Vhp = QKVb + 2 * T;

    convert_weights<<<1412, 256, 0, stream>>>(wq_o, wkv_o, wg_o, wq_i, wkv_i, wg_i,
                                              wo_o, wo_i, w1, b1, w2,
                                              WQKVG_O, WQKVG_I, WOT_O, WOT_I,
                                              W1PT, W2T, B1P);

    dim3 gQKVG(MROWS / 128, 4), gOUT(MROWS / 128, 1), gW1(MROWS / 128, 8);
    dim3 gFF2(MROWS / 64, 1);

    // ---- stage 1: row attention, x -> X (OUT fuses LN2 + stage-2 bias proj) ----
    ln_bias_kernel<<<MROWS / 4, 256, 0, stream>>>(x, lng_o, lnb_o, wb_o, XA, BIASb);
    mfma_gemm<EPI_QKVG, 128, 128><<<gQKVG, 256, 0, stream>>>(
        XA, WQKVG_O, bg_o, nullptr, nullptr, QKVb, Gb,
        nullptr, nullptr, nullptr, nullptr, nullptr, 0);
    attn_mfma_kernel<<<NSEQ * NH, 256, 0, stream>>>(Qhp, Khp, Vhp, BIASb, Gb, TMP);
    mfma_gemm<EPI_OUT, 128, 128><<<gOUT, 256, 0, stream>>>(
        TMP, WOT_O, bo_o, x, X, nullptr, nullptr,
        lng_i, lnb_i, wb_i, BIASb, XA, 0);

    // ---- stage 2: col attention, X -> X in place (OUT fuses final LN) ----
    mfma_gemm<EPI_QKVG, 128, 128><<<gQKVG, 256, 0, stream>>>(
        XA, WQKVG_I, bg_i, nullptr, nullptr, QKVb, Gb,
        nullptr, nullptr, nullptr, nullptr, nullptr, 0);
    attn_mfma_kernel<<<NSEQ * NH, 256, 0, stream>>>(Qhp, Khp, Vhp, BIASb, Gb, TMP);
    mfma_gemm<EPI_OUT, 128, 128><<<gOUT, 256, 0, stream>>>(
        TMP, WOT_I, bo_i, X, X, nullptr, nullptr,
        lng_f, lnb_f, nullptr, nullptr, XA, 1);

    // ---- FFN: H2 = geglu(XA@w1p+b1p); out = H2@w2 + b2 + X ----
    mfma_gemm<EPI_GEGLU, 128, 128><<<gW1, 256, 0, stream>>>(
        XA, W1PT, B1P, nullptr, nullptr, H2, nullptr,
        nullptr, nullptr, nullptr, nullptr, nullptr, 0);
    mfma_gemm<EPI_FF2, 64, 512><<<gFF2, 256, 0, stream>>>(
        H2, W2T, b2, X, (float*)d_out, nullptr, nullptr,
        nullptr, nullptr, nullptr, nullptr, nullptr, 0);
}